// Round 5
// baseline (415.725 us; speedup 1.0000x reference)
//
#include <hip/hip_runtime.h>

#define NPTS  32768
#define KNB   16
#define CINC  256
#define PEC   32
#define HWN   16
#define CMID  288
#define L1OUT 1024
#define COUTC 512
#define EPSLN 1e-5f
#define PBLK  16
#define W2LD  272   // w2s leading dim (mod 32 == 16 -> 2-way write conflict, free)

typedef __attribute__((ext_vector_type(8))) short short8;
typedef __attribute__((ext_vector_type(4))) float f32x4;
typedef __attribute__((ext_vector_type(2))) float f32x2;

__device__ __forceinline__ float leaky(float x) { return x > 0.f ? x : 0.1f * x; }

__device__ __forceinline__ float bf2f(unsigned short u) {
    union { unsigned int i; float f; } x; x.i = ((unsigned int)u) << 16; return x.f;
}
__device__ __forceinline__ unsigned short f2bf(float f) {
    unsigned int x = __float_as_uint(f);
    x = (x + 0x7fffu + ((x >> 16) & 1u)) >> 16;
    return (unsigned short)x;
}

__device__ __forceinline__ f32x2 lo2(f32x4 v) { return __builtin_shufflevector(v, v, 0, 1); }
__device__ __forceinline__ f32x2 hi2(f32x4 v) { return __builtin_shufflevector(v, v, 2, 3); }

// ---- packed fp32 FMA (VOP3P). Elementwise: d += a*b (all VGPR) ----
__device__ __forceinline__ void pkfma(f32x2& d, f32x2 a, f32x2 b) {
    asm("v_pk_fma_f32 %0, %1, %2, %0" : "+v"(d) : "v"(a), "v"(b));
}
__device__ __forceinline__ void pkfma_lo(f32x2& d, f32x2 a, f32x2 b) {
    asm("v_pk_fma_f32 %0, %1, %2, %0 op_sel:[0,0,0] op_sel_hi:[0,1,1]" : "+v"(d) : "v"(a), "v"(b));
}
__device__ __forceinline__ void pkfma_hi(f32x2& d, f32x2 a, f32x2 b) {
    asm("v_pk_fma_f32 %0, %1, %2, %0 op_sel:[1,0,0] op_sel_hi:[1,1,1]" : "+v"(d) : "v"(a), "v"(b));
}
// ---- scalar-operand variants: weight operand consumed from SGPR pair ----
__device__ __forceinline__ void pkfma_lo_s(f32x2& d, f32x2 a, f32x2 b) {
    asm("v_pk_fma_f32 %0, %1, %2, %0 op_sel:[0,0,0] op_sel_hi:[0,1,1]" : "+v"(d) : "v"(a), "s"(b));
}
__device__ __forceinline__ void pkfma_hi_s(f32x2& d, f32x2 a, f32x2 b) {
    asm("v_pk_fma_f32 %0, %1, %2, %0 op_sel:[1,0,0] op_sel_hi:[1,1,1]" : "+v"(d) : "v"(a), "s"(b));
}
__device__ __forceinline__ void pkfma_s0(f32x2& d, f32x2 a, f32x2 b) {
    asm("v_pk_fma_f32 %0, %1, %2, %0" : "+v"(d) : "s"(a), "v"(b));
}

// async global->LDS, 16B per lane, dest = wave-uniform base + lane*16
__device__ __forceinline__ void gld_lds16(const unsigned short* g, unsigned short* l) {
    __builtin_amdgcn_global_load_lds(
        (const __attribute__((address_space(1))) unsigned int*)g,
        (__attribute__((address_space(3))) unsigned int*)l,
        16, 0, 0);
}
__device__ __forceinline__ void gld_lds16f(const float* g, float* l) {
    __builtin_amdgcn_global_load_lds(
        (const __attribute__((address_space(1))) unsigned int*)g,
        (__attribute__((address_space(3))) unsigned int*)l,
        16, 0, 0);
}

// BK=32 staging (128x32 tile), XOR swz (row&3)<<3 matched by readers
__device__ __forceinline__ void stage_tile(const unsigned short* __restrict__ g,
                                           size_t ld, int row0, int k0,
                                           unsigned short* lds, int wave, int lane)
{
    #pragma unroll
    for (int r = 0; r < 2; ++r) {
        int e   = r * 2048 + wave * 512 + lane * 8;
        int row = e >> 5;
        int kp  = e & 31;
        int kl  = kp ^ ((row & 3) << 3);
        const unsigned short* src = g + (size_t)(row0 + row) * ld + (k0 + kl);
        gld_lds16(src, lds + r * 2048 + wave * 512);
    }
}

// BK=64 staging (128x64 tile). Row stride 128B is bank-constant, so the
// swizzle must spread 8 rows: kl = kp ^ ((row&7)<<3) -> 8 distinct 16B
// slots -> 2-way (free). Linear LDS dest + pre-swizzled SOURCE, reader
// applies the same XOR (both-sides rule).
__device__ __forceinline__ void stage_tile64(const unsigned short* __restrict__ g,
                                             size_t ld, int row0, int k0,
                                             unsigned short* lds, int wave, int lane)
{
    #pragma unroll
    for (int r = 0; r < 4; ++r) {
        int e   = r * 2048 + wave * 512 + lane * 8;
        int row = e >> 6;
        int kp  = e & 63;
        int kl  = kp ^ ((row & 7) << 3);
        const unsigned short* src = g + (size_t)(row0 + row) * ld + (k0 + kl);
        gld_lds16(src, lds + r * 2048 + wave * 512);
    }
}

// ---------------------------------------------------------------------------
// Stats kernel (parallel, 66 blocks): folded LN(256) stats of wn3.
// st layout: G @0 (256), wm3 @256 (16), gb @272 (16), bm3 @288, bsq @289.
// ---------------------------------------------------------------------------
__global__ __launch_bounds__(256) void wn3_stats_kernel(
    const float* __restrict__ W3, const float* __restrict__ b3, float* __restrict__ st)
{
    const int b = blockIdx.x;
    const int t = threadIdx.x;
    const int lane = t & 63, wave = t >> 6;
    const int c0 = lane * 4;

    if (b < 64) {
        int pair = b * 4 + wave;
        int h = pair >> 4, hp = pair & 15;
        f32x4 a  = *(const f32x4*)(W3 + h * CINC + c0);
        f32x4 bb = *(const f32x4*)(W3 + hp * CINC + c0);
        float g = a[0] * bb[0] + a[1] * bb[1] + a[2] * bb[2] + a[3] * bb[3];
        #pragma unroll
        for (int off = 1; off < 64; off <<= 1) g += __shfl_xor(g, off);
        if (lane == 0) st[pair] = g * (1.f / CINC);
    } else if (b == 64) {
        #pragma unroll
        for (int i = 0; i < 4; ++i) {
            int h = wave * 4 + i;
            f32x4 w  = *(const f32x4*)(W3 + h * CINC + c0);
            f32x4 bb = *(const f32x4*)(b3 + c0);
            float s  = w[0] + w[1] + w[2] + w[3];
            float sb = w[0] * bb[0] + w[1] * bb[1] + w[2] * bb[2] + w[3] * bb[3];
            #pragma unroll
            for (int off = 1; off < 64; off <<= 1) { s += __shfl_xor(s, off); sb += __shfl_xor(sb, off); }
            if (lane == 0) { st[256 + h] = s * (1.f / CINC); st[272 + h] = sb * (1.f / CINC); }
        }
    } else if (wave == 0) {
        f32x4 bb = *(const f32x4*)(b3 + c0);
        float s = bb[0] + bb[1] + bb[2] + bb[3];
        float q = bb[0] * bb[0] + bb[1] * bb[1] + bb[2] * bb[2] + bb[3] * bb[3];
        #pragma unroll
        for (int off = 1; off < 64; off <<= 1) { s += __shfl_xor(s, off); q += __shfl_xor(q, off); }
        if (lane == 0) { st[288] = s * (1.f / CINC); st[289] = q * (1.f / CINC); }
    }
}

// ---------------------------------------------------------------------------
// Fused edge kernel, R11 (FROZEN — verified 155 us, VALUBusy 57%).
// ---------------------------------------------------------------------------
__global__ __launch_bounds__(256, 3) void edge_fused_kernel(
    const float* __restrict__ xyz, const unsigned short* __restrict__ featsb,
    const int* __restrict__ nei,
    const float* __restrict__ pe_w1, const float* __restrict__ pe_b1,
    const float* __restrict__ pe_g1, const float* __restrict__ pe_be1,
    const float* __restrict__ pe_w2, const float* __restrict__ pe_b2,
    const float* __restrict__ pe_g2, const float* __restrict__ pe_be2,
    const float* __restrict__ wn_w1, const float* __restrict__ wn_b1,
    const float* __restrict__ wn_g1, const float* __restrict__ wn_be1,
    const float* __restrict__ wn_w2, const float* __restrict__ wn_b2,
    const float* __restrict__ wn_g2, const float* __restrict__ wn_be2,
    const float* __restrict__ st,
    const float* __restrict__ wn_w3, const float* __restrict__ wn_b3,
    const float* __restrict__ wn_g3, const float* __restrict__ wn_be3,
    const float* __restrict__ nm_g, const float* __restrict__ nm_b,
    unsigned short* __restrict__ xln)
{
    __shared__ __align__(16) float W3s[16 * 256];             // 16 KB
    __shared__ __align__(16) float w2s[PBLK * W2LD];          // 17 KB [lp][hh*16+k]
    __shared__ __align__(16) float rms[PBLK * 16];
    __shared__ __align__(16) float mus[PBLK * 16];
    __shared__ float pes[PBLK * 32];

    const int t = threadIdx.x;

    // ---- async-stage wn_w3 into LDS; drained by the Phase-A/B barrier ----
    {
        const int lane = t & 63, wave = t >> 6;
        #pragma unroll
        for (int r = 0; r < 4; ++r) {
            int base = (wave * 4 + r) * 256;           // one 1KB row per iter
            gld_lds16f(wn_w3 + base + lane * 4, W3s + base);
        }
    }

    // ======================= Phase A: per-edge MLPs =======================
    {
        const int lp = t >> 4, kk = t & 15;
        const int m = blockIdx.x * PBLK + lp;
        const int n = nei[m * KNB + kk];
        const float lx = xyz[n * 3 + 0] - xyz[m * 3 + 0];
        const float ly = xyz[n * 3 + 1] - xyz[m * 3 + 1];
        const float lz = xyz[n * 3 + 2] - xyz[m * 3 + 2];

        // ---- WN layer 1 (scalar, small) -> pairs ----
        f32x2 w1p[8];
        float s = 0.f, q = 0.f;
        #pragma unroll
        for (int c4 = 0; c4 < 4; ++c4) {
            f32x4 wa = *(const f32x4*)&wn_w1[c4 * 4];
            f32x4 wb = *(const f32x4*)&wn_w1[16 + c4 * 4];
            f32x4 wc = *(const f32x4*)&wn_w1[32 + c4 * 4];
            f32x4 bb = *(const f32x4*)&wn_b1[c4 * 4];
            #pragma unroll
            for (int j = 0; j < 4; ++j) {
                float v = bb[j] + lx * wa[j] + ly * wb[j] + lz * wc[j];
                int c = c4 * 4 + j;
                w1p[c >> 1][c & 1] = v; s += v; q += v * v;
            }
        }
        float mu = s * (1.f / 16.f);
        float rstd = rsqrtf(q * (1.f / 16.f) - mu * mu + EPSLN);
        #pragma unroll
        for (int c4 = 0; c4 < 4; ++c4) {
            f32x4 g = *(const f32x4*)&wn_g1[c4 * 4];
            f32x4 be = *(const f32x4*)&wn_be1[c4 * 4];
            #pragma unroll
            for (int j = 0; j < 4; ++j) {
                int c = c4 * 4 + j;
                w1p[c >> 1][c & 1] = leaky((w1p[c >> 1][c & 1] - mu) * rstd * g[j] + be[j]);
            }
        }

        // ---- WN layer 2 (packed fma, weights via SGPR) ----
        f32x2 w2p[8];
        #pragma unroll
        for (int c4 = 0; c4 < 4; ++c4) {
            f32x4 bb = *(const f32x4*)&wn_b2[c4 * 4];
            w2p[c4 * 2] = lo2(bb); w2p[c4 * 2 + 1] = hi2(bb);
        }
        #pragma unroll 2
        for (int jp = 0; jp < 8; ++jp) {
            f32x2 hp = w1p[jp];
            #pragma unroll
            for (int c4 = 0; c4 < 4; ++c4) {
                f32x4 w = *(const f32x4*)&wn_w2[(2 * jp) * 16 + c4 * 4];
                pkfma_lo_s(w2p[c4 * 2], hp, lo2(w));
                pkfma_lo_s(w2p[c4 * 2 + 1], hp, hi2(w));
            }
            #pragma unroll
            for (int c4 = 0; c4 < 4; ++c4) {
                f32x4 w = *(const f32x4*)&wn_w2[(2 * jp + 1) * 16 + c4 * 4];
                pkfma_hi_s(w2p[c4 * 2], hp, lo2(w));
                pkfma_hi_s(w2p[c4 * 2 + 1], hp, hi2(w));
            }
        }
        s = 0.f; q = 0.f;
        #pragma unroll
        for (int i = 0; i < 8; ++i) {
            s += w2p[i][0] + w2p[i][1];
            q += w2p[i][0] * w2p[i][0] + w2p[i][1] * w2p[i][1];
        }
        mu = s * (1.f / 16.f);
        rstd = rsqrtf(q * (1.f / 16.f) - mu * mu + EPSLN);
        #pragma unroll
        for (int c4 = 0; c4 < 4; ++c4) {
            f32x4 g = *(const f32x4*)&wn_g2[c4 * 4];
            f32x4 be = *(const f32x4*)&wn_be2[c4 * 4];
            #pragma unroll
            for (int j = 0; j < 4; ++j) {
                int c = c4 * 4 + j;
                w2p[c >> 1][c & 1] = leaky((w2p[c >> 1][c & 1] - mu) * rstd * g[j] + be[j]);
            }
        }

        // ---- folded LN(256) stats (G matrix via SGPR operand) ----
        float mu3 = st[288];
        #pragma unroll
        for (int h4 = 0; h4 < 4; ++h4) {
            f32x4 wm = *(const f32x4*)&st[256 + h4 * 4];
            mu3 += wm[0] * w2p[h4 * 2][0] + wm[1] * w2p[h4 * 2][1]
                 + wm[2] * w2p[h4 * 2 + 1][0] + wm[3] * w2p[h4 * 2 + 1][1];
        }
        float esq = st[289];
        #pragma unroll 4
        for (int hh = 0; hh < 16; ++hh) {
            f32x2 acc2 = {0.f, 0.f};
            #pragma unroll
            for (int h4 = 0; h4 < 4; ++h4) {
                f32x4 g = *(const f32x4*)&st[hh * 16 + h4 * 4];
                pkfma_s0(acc2, lo2(g), w2p[h4 * 2]);
                pkfma_s0(acc2, hi2(g), w2p[h4 * 2 + 1]);
            }
            float acc = acc2[0] + acc2[1] + 2.f * st[272 + hh];
            esq += w2p[hh >> 1][hh & 1] * acc;
        }
        float r3 = rsqrtf(esq - mu3 * mu3 + EPSLN);

        #pragma unroll
        for (int hh = 0; hh < 16; ++hh)
            w2s[lp * W2LD + hh * 16 + kk] = w2p[hh >> 1][hh & 1];
        rms[lp * 16 + kk] = r3;
        mus[lp * 16 + kk] = mu3;

        // ---- PE layer 1 (scalar) -> pairs ----
        f32x2 h2[16];
        s = 0.f; q = 0.f;
        #pragma unroll
        for (int c4 = 0; c4 < 8; ++c4) {
            f32x4 wa = *(const f32x4*)&pe_w1[c4 * 4];
            f32x4 wb = *(const f32x4*)&pe_w1[32 + c4 * 4];
            f32x4 wc = *(const f32x4*)&pe_w1[64 + c4 * 4];
            f32x4 bb = *(const f32x4*)&pe_b1[c4 * 4];
            #pragma unroll
            for (int j = 0; j < 4; ++j) {
                float v = bb[j] + lx * wa[j] + ly * wb[j] + lz * wc[j];
                int c = c4 * 4 + j;
                h2[c >> 1][c & 1] = v; s += v; q += v * v;
            }
        }
        mu = s * (1.f / 32.f);
        rstd = rsqrtf(q * (1.f / 32.f) - mu * mu + EPSLN);
        #pragma unroll
        for (int c4 = 0; c4 < 8; ++c4) {
            f32x4 g = *(const f32x4*)&pe_g1[c4 * 4];
            f32x4 be = *(const f32x4*)&pe_be1[c4 * 4];
            #pragma unroll
            for (int j = 0; j < 4; ++j) {
                int c = c4 * 4 + j;
                h2[c >> 1][c & 1] = leaky((h2[c >> 1][c & 1] - mu) * rstd * g[j] + be[j]);
            }
        }

        // ---- PE layer 2 (packed fma, weights via SGPR) ----
        f32x2 f2[16];
        #pragma unroll
        for (int c4 = 0; c4 < 8; ++c4) {
            f32x4 bb = *(const f32x4*)&pe_b2[c4 * 4];
            f2[c4 * 2] = lo2(bb); f2[c4 * 2 + 1] = hi2(bb);
        }
        #pragma unroll 2
        for (int jp = 0; jp < 16; ++jp) {
            f32x2 hp = h2[jp];
            #pragma unroll
            for (int c4 = 0; c4 < 8; ++c4) {
                f32x4 w = *(const f32x4*)&pe_w2[(2 * jp) * 32 + c4 * 4];
                pkfma_lo_s(f2[c4 * 2], hp, lo2(w));
                pkfma_lo_s(f2[c4 * 2 + 1], hp, hi2(w));
            }
            #pragma unroll
            for (int c4 = 0; c4 < 8; ++c4) {
                f32x4 w = *(const f32x4*)&pe_w2[(2 * jp + 1) * 32 + c4 * 4];
                pkfma_hi_s(f2[c4 * 2], hp, lo2(w));
                pkfma_hi_s(f2[c4 * 2 + 1], hp, hi2(w));
            }
        }
        s = 0.f; q = 0.f;
        #pragma unroll
        for (int i = 0; i < 16; ++i) {
            s += f2[i][0] + f2[i][1];
            q += f2[i][0] * f2[i][0] + f2[i][1] * f2[i][1];
        }
        mu = s * (1.f / 32.f);
        rstd = rsqrtf(q * (1.f / 32.f) - mu * mu + EPSLN);
        #pragma unroll
        for (int c4 = 0; c4 < 8; ++c4) {
            f32x4 g = *(const f32x4*)&pe_g2[c4 * 4];
            f32x4 be = *(const f32x4*)&pe_be2[c4 * 4];
            #pragma unroll
            for (int j = 0; j < 4; ++j) {
                int c = c4 * 4 + j;
                float v = (f2[c >> 1][c & 1] - mu) * rstd * g[j] + be[j];
                v += __shfl_xor(v, 1);
                v += __shfl_xor(v, 2);
                v += __shfl_xor(v, 4);
                v += __shfl_xor(v, 8);
                if (kk == 0) pes[lp * 32 + c] = v;
            }
        }
    }
    __syncthreads();   // orders w2s/rms/mus/pes writes AND drains W3s async stage

    // ======================= Phase B: per-point aggregation ================
    const int lane = t & 63, wave = t >> 6;
    const int c0 = lane * 4;
    const f32x4 b3r  = *(const f32x4*)(wn_b3 + c0);
    const f32x4 g3r  = *(const f32x4*)(wn_g3 + c0);
    const f32x4 be3r = *(const f32x4*)(wn_be3 + c0);

    for (int pp = 0; pp < 4; ++pp) {
        const int lp = wave * 4 + pp;
        const int p  = blockIdx.x * PBLK + lp;
        const int* np = nei + p * KNB;

        // raw2[k][cp]: k = neighbor, cp = channel pair (c0+0/1, c0+2/3)
        f32x2 raw2[16][2];
        #pragma unroll
        for (int k = 0; k < 16; ++k) {
            raw2[k][0] = (f32x2){0.f, 0.f};
            raw2[k][1] = (f32x2){0.f, 0.f};
        }

        #pragma unroll 2
        for (int hh = 0; hh < 16; ++hh) {
            f32x4 w3r = *(const f32x4*)&W3s[hh * 256 + c0];
            f32x2 w01 = lo2(w3r), w23 = hi2(w3r);
            f32x4 u0 = *(const f32x4*)&w2s[lp * W2LD + hh * 16 + 0];
            f32x4 u1 = *(const f32x4*)&w2s[lp * W2LD + hh * 16 + 4];
            f32x4 u2 = *(const f32x4*)&w2s[lp * W2LD + hh * 16 + 8];
            f32x4 u3 = *(const f32x4*)&w2s[lp * W2LD + hh * 16 + 12];
            f32x2 p0 = lo2(u0), p1 = hi2(u0), p2 = lo2(u1), p3 = hi2(u1);
            f32x2 p4 = lo2(u2), p5 = hi2(u2), p6 = lo2(u3), p7 = hi2(u3);
            pkfma_lo(raw2[ 0][0], p0, w01); pkfma_lo(raw2[ 0][1], p0, w23);
            pkfma_hi(raw2[ 1][0], p0, w01); pkfma_hi(raw2[ 1][1], p0, w23);
            pkfma_lo(raw2[ 2][0], p1, w01); pkfma_lo(raw2[ 2][1], p1, w23);
            pkfma_hi(raw2[ 3][0], p1, w01); pkfma_hi(raw2[ 3][1], p1, w23);
            pkfma_lo(raw2[ 4][0], p2, w01); pkfma_lo(raw2[ 4][1], p2, w23);
            pkfma_hi(raw2[ 5][0], p2, w01); pkfma_hi(raw2[ 5][1], p2, w23);
            pkfma_lo(raw2[ 6][0], p3, w01); pkfma_lo(raw2[ 6][1], p3, w23);
            pkfma_hi(raw2[ 7][0], p3, w01); pkfma_hi(raw2[ 7][1], p3, w23);
            pkfma_lo(raw2[ 8][0], p4, w01); pkfma_lo(raw2[ 8][1], p4, w23);
            pkfma_hi(raw2[ 9][0], p4, w01); pkfma_hi(raw2[ 9][1], p4, w23);
            pkfma_lo(raw2[10][0], p5, w01); pkfma_lo(raw2[10][1], p5, w23);
            pkfma_hi(raw2[11][0], p5, w01); pkfma_hi(raw2[11][1], p5, w23);
            pkfma_lo(raw2[12][0], p6, w01); pkfma_lo(raw2[12][1], p6, w23);
            pkfma_hi(raw2[13][0], p6, w01); pkfma_hi(raw2[13][1], p6, w23);
            pkfma_lo(raw2[14][0], p7, w01); pkfma_lo(raw2[14][1], p7, w23);
            pkfma_hi(raw2[15][0], p7, w01); pkfma_hi(raw2[15][1], p7, w23);
        }

        float agg[4] = {0.f, 0.f, 0.f, 0.f};
        #pragma unroll
        for (int k4 = 0; k4 < 4; ++k4) {
            f32x4 rkv = *(const f32x4*)&rms[lp * 16 + k4 * 4];
            f32x4 muv = *(const f32x4*)&mus[lp * 16 + k4 * 4];
            #pragma unroll
            for (int r = 0; r < 4; ++r) {
                int k = k4 * 4 + r;
                int nk = np[k];
                float rk  = rkv[r];
                float muk = muv[r];
                ushort4 fu = *(const ushort4*)(featsb + (size_t)nk * CINC + c0);
                float w3x = (raw2[k][0][0] + b3r[0] - muk) * rk * g3r[0] + be3r[0];
                float w3y = (raw2[k][0][1] + b3r[1] - muk) * rk * g3r[1] + be3r[1];
                float w3z = (raw2[k][1][0] + b3r[2] - muk) * rk * g3r[2] + be3r[2];
                float w3w = (raw2[k][1][1] + b3r[3] - muk) * rk * g3r[3] + be3r[3];
                agg[0] += bf2f(fu.x) * w3x;
                agg[1] += bf2f(fu.y) * w3y;
                agg[2] += bf2f(fu.z) * w3z;
                agg[3] += bf2f(fu.w) * w3w;
            }
        }

        float pv = (lane < 32) ? pes[lp * 32 + lane] : 0.f;

        float s = agg[0] + agg[1] + agg[2] + agg[3];
        float q = agg[0] * agg[0] + agg[1] * agg[1] + agg[2] * agg[2] + agg[3] * agg[3];
        if (lane < 32) { s += pv; q += pv * pv; }
        #pragma unroll
        for (int off = 1; off < 64; off <<= 1) {
            s += __shfl_xor(s, off);
            q += __shfl_xor(q, off);
        }
        float mu = s * (1.f / 288.f);
        float rstd = rsqrtf(q * (1.f / 288.f) - mu * mu + EPSLN);

        f32x4 ngr = *(const f32x4*)(nm_g + c0);
        f32x4 nbr = *(const f32x4*)(nm_b + c0);
        unsigned short* xp = xln + (size_t)p * CMID;
        ushort4 o;
        o.x = f2bf((agg[0] - mu) * rstd * ngr[0] + nbr[0]);
        o.y = f2bf((agg[1] - mu) * rstd * ngr[1] + nbr[1]);
        o.z = f2bf((agg[2] - mu) * rstd * ngr[2] + nbr[2]);
        o.w = f2bf((agg[3] - mu) * rstd * ngr[3] + nbr[3]);
        *(ushort4*)(xp + c0) = o;
        if (lane < 32)
            xp[256 + lane] = f2bf((pv - mu) * rstd * nm_g[256 + lane] + nm_b[256 + lane]);
    }
}

// ---------------------------------------------------------------------------
// Conversion kernels
// ---------------------------------------------------------------------------
__global__ __launch_bounds__(256) void transpose_bf16_kernel(
    const float* __restrict__ src, unsigned short* __restrict__ dst, int K, int N)
{
    __shared__ float tile[32][33];
    const int k0 = blockIdx.y * 32, n0 = blockIdx.x * 32;
    const int tx = threadIdx.x & 31, ty = threadIdx.x >> 5;
    #pragma unroll
    for (int i = ty; i < 32; i += 8)
        tile[i][tx] = src[(size_t)(k0 + i) * N + n0 + tx];
    __syncthreads();
    #pragma unroll
    for (int i = ty; i < 32; i += 8)
        dst[(size_t)(n0 + i) * K + k0 + tx] = f2bf(tile[tx][i]);
}

__global__ __launch_bounds__(256) void feats_bf16_kernel(
    const float* __restrict__ src, unsigned short* __restrict__ dst)
{
    int i = (blockIdx.x * 256 + threadIdx.x) * 4;
    float4 v = *(const float4*)(src + i);
    ushort4 o;
    o.x = f2bf(v.x); o.y = f2bf(v.y); o.z = f2bf(v.z); o.w = f2bf(v.w);
    *(ushort4*)(dst + i) = o;
}

// ---------------------------------------------------------------------------
// GEMM 1: h1 = leaky(xln @ l1_w + l1_b), bf16 MFMA, 128x128, BK=32
// (K=288 not 64-divisible; kept at BK=32)
// ---------------------------------------------------------------------------
__global__ __launch_bounds__(256) void gemm1_mfma(
    const unsigned short* __restrict__ A,
    const unsigned short* __restrict__ BT,
    const float* __restrict__ bias,
    unsigned short* __restrict__ C)
{
    __shared__ unsigned short As[128 * 32];
    __shared__ unsigned short Bs[128 * 32];
    const int t = threadIdx.x;
    const int lane = t & 63, wave = t >> 6;
    const int wm = wave >> 1, wn = wave & 1;
    const int m0 = blockIdx.y * 128, n0 = blockIdx.x * 128;
    const int l15 = lane & 15, j0 = (lane >> 4) << 3;

    f32x4 zero = {0.f, 0.f, 0.f, 0.f};
    f32x4 acc[4][4];
    #pragma unroll
    for (int i = 0; i < 4; ++i)
        #pragma unroll
        for (int j = 0; j < 4; ++j) acc[i][j] = zero;

    for (int kt = 0; kt < CMID; kt += 32) {
        stage_tile(A,  CMID, m0, kt, As, wave, lane);
        stage_tile(BT, CMID, n0, kt, Bs, wave, lane);
        __syncthreads();
        short8 af[4], bf[4];
        #pragma unroll
        for (int i = 0; i < 4; ++i) {
            int ar = wm * 64 + i * 16 + l15;
            af[i] = *(const short8*)&As[ar * 32 + (j0 ^ ((ar & 3) << 3))];
            int br = wn * 64 + i * 16 + l15;
            bf[i] = *(const short8*)&Bs[br * 32 + (j0 ^ ((br & 3) << 3))];
        }
        #pragma unroll
        for (int i = 0; i < 4; ++i)
            #pragma unroll
            for (int j = 0; j < 4; ++j)
                acc[i][j] = __builtin_amdgcn_mfma_f32_16x16x32_bf16(af[i], bf[j], acc[i][j], 0, 0, 0);
        __syncthreads();
    }

    const int q = lane >> 4;
    #pragma unroll
    for (int j = 0; j < 4; ++j) {
        int ncol = n0 + wn * 64 + j * 16 + l15;
        float bv = bias[ncol];
        #pragma unroll
        for (int i = 0; i < 4; ++i) {
            int mbase = m0 + wm * 64 + i * 16 + q * 4;
            #pragma unroll
            for (int r = 0; r < 4; ++r)
                C[(size_t)(mbase + r) * L1OUT + ncol] = f2bf(leaky(acc[i][j][r] + bv));
        }
    }
}

// ---------------------------------------------------------------------------
// GEMM 2 (R12): dual-K bf16 MFMA, 128x128 tile, BK=64.
// K-iterations 40 -> 20: halves the per-iteration vmcnt(0)+barrier drains
// (the m97-structure stall). 32 MFMA per barrier pair. LDS 32 KB.
// ---------------------------------------------------------------------------
__global__ __launch_bounds__(256) void gemm2_mfma(
    const unsigned short* __restrict__ H,
    const unsigned short* __restrict__ W2T,
    const unsigned short* __restrict__ F,
    const unsigned short* __restrict__ WscT,
    const float* __restrict__ b2, const float* __restrict__ bsc,
    float* __restrict__ Out)
{
    __shared__ unsigned short As[128 * 64];
    __shared__ unsigned short Bs[128 * 64];
    const int t = threadIdx.x;
    const int lane = t & 63, wave = t >> 6;
    const int wm = wave >> 1, wn = wave & 1;
    const int m0 = blockIdx.y * 128, n0 = blockIdx.x * 128;
    const int l15 = lane & 15, j0 = (lane >> 4) << 3;

    f32x4 zero = {0.f, 0.f, 0.f, 0.f};
    f32x4 acc[4][4];
    #pragma unroll
    for (int i = 0; i < 4; ++i)
        #pragma unroll
        for (int j = 0; j < 4; ++j) acc[i][j] = zero;

    for (int kt = 0; kt < L1OUT; kt += 64) {
        stage_tile64(H,   L1OUT, m0, kt, As, wave, lane);
        stage_tile64(W2T, L1OUT, n0, kt, Bs, wave, lane);
        __syncthreads();
        #pragma unroll
        for (int h = 0; h < 2; ++h) {
            short8 af[4], bf[4];
            #pragma unroll
            for (int i = 0; i < 4; ++i) {
                int ar = wm * 64 + i * 16 + l15;
                af[i] = *(const short8*)&As[ar * 64 + ((h * 32 + j0) ^ ((ar & 7) << 3))];
                int br = wn * 64 + i * 16 + l15;
                bf[i] = *(const short8*)&Bs[br * 64 + ((h * 32 + j0) ^ ((br & 7) << 3))];
            }
            #pragma unroll
            for (int i = 0; i < 4; ++i)
                #pragma unroll
                for (int j = 0; j < 4; ++j)
                    acc[i][j] = __builtin_amdgcn_mfma_f32_16x16x32_bf16(af[i], bf[j], acc[i][j], 0, 0, 0);
        }
        __syncthreads();
    }
    for (int kt = 0; kt < CINC; kt += 64) {
        stage_tile64(F,    CINC, m0, kt, As, wave, lane);
        stage_tile64(WscT, CINC, n0, kt, Bs, wave, lane);
        __syncthreads();
        #pragma unroll
        for (int h = 0; h < 2; ++h) {
            short8 af[4], bf[4];
            #pragma unroll
            for (int i = 0; i < 4; ++i) {
                int ar = wm * 64 + i * 16 + l15;
                af[i] = *(const short8*)&As[ar * 64 + ((h * 32 + j0) ^ ((ar & 7) << 3))];
                int br = wn * 64 + i * 16 + l15;
                bf[i] = *(const short8*)&Bs[br * 64 + ((h * 32 + j0) ^ ((br & 7) << 3))];
            }
            #pragma unroll
            for (int i = 0; i < 4; ++i)
                #pragma unroll
                for (int j = 0; j < 4; ++j)
                    acc[i][j] = __builtin_amdgcn_mfma_f32_16x16x32_bf16(af[i], bf[j], acc[i][j], 0, 0, 0);
        }
        __syncthreads();
    }

    const int q = lane >> 4;
    #pragma unroll
    for (int j = 0; j < 4; ++j) {
        int ncol = n0 + wn * 64 + j * 16 + l15;
        float bv = b2[ncol] + bsc[ncol];
        #pragma unroll
        for (int i = 0; i < 4; ++i) {
            int mbase = m0 + wm * 64 + i * 16 + q * 4;
            #pragma unroll
            for (int r = 0; r < 4; ++r)
                Out[(size_t)(mbase + r) * COUTC + ncol] = leaky(acc[i][j][r] + bv);
        }
    }
}

extern "C" void kernel_launch(void* const* d_in, const int* in_sizes, int n_in,
                              void* d_out, int out_size, void* d_ws, size_t ws_size,
                              hipStream_t stream)
{
    const float* xyz    = (const float*)d_in[0];
    const float* feats  = (const float*)d_in[1];
    const int*   nei    = (const int*)d_in[2];
    const float* pe_w1  = (const float*)d_in[3];
    const float* pe_b1  = (const float*)d_in[4];
    const float* pe_g1  = (const float*)d_in[5];
    const float* pe_be1 = (const float*)d_in[6];
    const float* pe_w2  = (const float*)d_in[7];
    const float* pe_b2  = (const float*)d_in[8];
    const float* pe_g2  = (const float*)d_in[9];
    const float* pe_be2 = (const float*)d_in[10];
    const float* wn_w1  = (const float*)d_in[11];
    const float* wn_b1  = (const float*)d_in[12];
    const float* wn_g1  = (const float*)d_in[13];
    const float* wn_be1 = (const float*)d_in[14];
    const float* wn_w2  = (const float*)d_in[15];
    const float* wn_b2  = (const float*)d_in[16];
    const float* wn_g2  = (const float*)d_in[17];
    const float* wn_be2 = (const float*)d_in[18];
    const float* wn_w3  = (const float*)d_in[19];
    const float* wn_b3  = (const float*)d_in[20];
    const float* wn_g3  = (const float*)d_in[21];
    const float* wn_be3 = (const float*)d_in[22];
    const float* nm_g   = (const float*)d_in[23];
    const float* nm_b   = (const float*)d_in[24];
    const float* l1_w   = (const float*)d_in[25];
    const float* l1_b   = (const float*)d_in[26];
    const float* l2_w   = (const float*)d_in[27];
    const float* l2_b   = (const float*)d_in[28];
    const float* sc_w   = (const float*)d_in[29];
    const float* sc_b   = (const float*)d_in[30];

    char* ws = (char*)d_ws;
    unsigned short* xln    = (unsigned short*)(ws);               // 18,874,368
    unsigned short* featsb = (unsigned short*)(ws + 18874368);    // 16,777,216
    unsigned short* l1_wT  = (unsigned short*)(ws + 35651584);    //    589,824
    unsigned short* l2_wT  = (unsigned short*)(ws + 36241408);    //  1,048,576
    unsigned short* sc_wT  = (unsigned short*)(ws + 37289984);    //    262,144
    float*          st     = (float*)(ws + 37552128);             //      4,096
    unsigned short* h1     = (unsigned short*)(ws + 37556224);    // 67,108,864

    wn3_stats_kernel<<<66, 256, 0, stream>>>(wn_w3, wn_b3, st);
    transpose_bf16_kernel<<<dim3(L1OUT / 32, CMID / 32), 256, 0, stream>>>(l1_w, l1_wT, CMID, L1OUT);
    transpose_bf16_kernel<<<dim3(COUTC / 32, L1OUT / 32), 256, 0, stream>>>(l2_w, l2_wT, L1OUT, COUTC);
    transpose_bf16_kernel<<<dim3(COUTC / 32, CINC / 32), 256, 0, stream>>>(sc_w, sc_wT, CINC, COUTC);
    feats_bf16_kernel<<<(NPTS * CINC / 4) / 256, 256, 0, stream>>>(feats, featsb);

    edge_fused_kernel<<<NPTS / PBLK, 256, 0, stream>>>(
        xyz, featsb, nei,
        pe_w1, pe_b1, pe_g1, pe_be1, pe_w2, pe_b2, pe_g2, pe_be2,
        wn_w1, wn_b1, wn_g1, wn_be1, wn_w2, wn_b2, wn_g2, wn_be2,
        st, wn_w3, wn_b3, wn_g3, wn_be3, nm_g, nm_b, xln);

    gemm1_mfma<<<dim3(L1OUT / 128, NPTS / 128), 256, 0, stream>>>(xln, l1_wT, l1_b, h1);

    gemm2_mfma<<<dim3(COUTC / 128, NPTS / 128), 256, 0, stream>>>(
        h1, l2_wT, featsb, sc_wT, l2_b, sc_b, (float*)d_out);
}

// Round 6
// 377.826 us; speedup vs baseline: 1.1003x; 1.1003x over previous
//
#include <hip/hip_runtime.h>

#define NPTS  32768
#define KNB   16
#define CINC  256
#define PEC   32
#define HWN   16
#define CMID  288
#define L1OUT 1024
#define COUTC 512
#define EPSLN 1e-5f
#define PBLK  16
#define W2LD  272   // w2s leading dim (mod 32 == 16 -> 2-way write conflict, free)

typedef __attribute__((ext_vector_type(8))) short short8;
typedef __attribute__((ext_vector_type(4))) float f32x4;
typedef __attribute__((ext_vector_type(2))) float f32x2;

__device__ __forceinline__ float leaky(float x) { return x > 0.f ? x : 0.1f * x; }

__device__ __forceinline__ float bf2f(unsigned short u) {
    union { unsigned int i; float f; } x; x.i = ((unsigned int)u) << 16; return x.f;
}
__device__ __forceinline__ unsigned short f2bf(float f) {
    unsigned int x = __float_as_uint(f);
    x = (x + 0x7fffu + ((x >> 16) & 1u)) >> 16;
    return (unsigned short)x;
}

__device__ __forceinline__ f32x2 lo2(f32x4 v) { return __builtin_shufflevector(v, v, 0, 1); }
__device__ __forceinline__ f32x2 hi2(f32x4 v) { return __builtin_shufflevector(v, v, 2, 3); }

// ---- packed fp32 FMA (VOP3P). Elementwise: d += a*b (all VGPR) ----
__device__ __forceinline__ void pkfma(f32x2& d, f32x2 a, f32x2 b) {
    asm("v_pk_fma_f32 %0, %1, %2, %0" : "+v"(d) : "v"(a), "v"(b));
}
__device__ __forceinline__ void pkfma_lo(f32x2& d, f32x2 a, f32x2 b) {
    asm("v_pk_fma_f32 %0, %1, %2, %0 op_sel:[0,0,0] op_sel_hi:[0,1,1]" : "+v"(d) : "v"(a), "v"(b));
}
__device__ __forceinline__ void pkfma_hi(f32x2& d, f32x2 a, f32x2 b) {
    asm("v_pk_fma_f32 %0, %1, %2, %0 op_sel:[1,0,0] op_sel_hi:[1,1,1]" : "+v"(d) : "v"(a), "v"(b));
}
// ---- scalar-operand variants: weight operand consumed from SGPR pair ----
__device__ __forceinline__ void pkfma_lo_s(f32x2& d, f32x2 a, f32x2 b) {
    asm("v_pk_fma_f32 %0, %1, %2, %0 op_sel:[0,0,0] op_sel_hi:[0,1,1]" : "+v"(d) : "v"(a), "s"(b));
}
__device__ __forceinline__ void pkfma_hi_s(f32x2& d, f32x2 a, f32x2 b) {
    asm("v_pk_fma_f32 %0, %1, %2, %0 op_sel:[1,0,0] op_sel_hi:[1,1,1]" : "+v"(d) : "v"(a), "s"(b));
}
__device__ __forceinline__ void pkfma_s0(f32x2& d, f32x2 a, f32x2 b) {
    asm("v_pk_fma_f32 %0, %1, %2, %0" : "+v"(d) : "s"(a), "v"(b));
}

// async global->LDS, 16B per lane, dest = wave-uniform base + lane*16
__device__ __forceinline__ void gld_lds16(const unsigned short* g, unsigned short* l) {
    __builtin_amdgcn_global_load_lds(
        (const __attribute__((address_space(1))) unsigned int*)g,
        (__attribute__((address_space(3))) unsigned int*)l,
        16, 0, 0);
}
__device__ __forceinline__ void gld_lds16f(const float* g, float* l) {
    __builtin_amdgcn_global_load_lds(
        (const __attribute__((address_space(1))) unsigned int*)g,
        (__attribute__((address_space(3))) unsigned int*)l,
        16, 0, 0);
}

// BK=32 staging (128x32 tile), XOR swz (row&3)<<3 matched by readers
__device__ __forceinline__ void stage_tile(const unsigned short* __restrict__ g,
                                           size_t ld, int row0, int k0,
                                           unsigned short* lds, int wave, int lane)
{
    #pragma unroll
    for (int r = 0; r < 2; ++r) {
        int e   = r * 2048 + wave * 512 + lane * 8;
        int row = e >> 5;
        int kp  = e & 31;
        int kl  = kp ^ ((row & 3) << 3);
        const unsigned short* src = g + (size_t)(row0 + row) * ld + (k0 + kl);
        gld_lds16(src, lds + r * 2048 + wave * 512);
    }
}

// XCD-aware bijective swizzle of the linear block id (T1; nwg % 8 == 0).
// Same-XCD blocks (lin % 8 == const) get a contiguous chunk of work ->
// shared A-panels hit that XCD's L2 instead of being refetched 8x.
__device__ __forceinline__ void xcd_swz(int gx, int& bx, int& by) {
    int lin = blockIdx.y * gx + blockIdx.x;
    int n   = gx * gridDim.y;
    int s   = (lin & 7) * (n >> 3) + (lin >> 3);
    bx = s % gx;
    by = s / gx;
}

// ---------------------------------------------------------------------------
// Merged prep kernel (R13): feats->bf16 cvt, 3 weight transposes, wn3 stats
// in ONE launch (all independent, read-only inputs). Block ranges:
//   [0, 8192)            feats cvt
//   [8192, 8480)         l1_w transpose  (32 x 9)
//   [8480, 8992)         l2_w transpose  (16 x 32)
//   [8992, 9120)         sc_w transpose  (16 x 8)
//   [9120, 9186)         wn3 stats (66 blocks)
// ---------------------------------------------------------------------------
__device__ __forceinline__ void transpose_body(
    const float* __restrict__ src, unsigned short* __restrict__ dst,
    int K, int N, int bx, int by, float (*tile)[33])
{
    const int k0 = by * 32, n0 = bx * 32;
    const int tx = threadIdx.x & 31, ty = threadIdx.x >> 5;
    #pragma unroll
    for (int i = ty; i < 32; i += 8)
        tile[i][tx] = src[(size_t)(k0 + i) * N + n0 + tx];
    __syncthreads();
    #pragma unroll
    for (int i = ty; i < 32; i += 8)
        dst[(size_t)(n0 + i) * K + k0 + tx] = f2bf(tile[tx][i]);
}

__global__ __launch_bounds__(256) void prep_kernel(
    const float* __restrict__ feats, unsigned short* __restrict__ featsb,
    const float* __restrict__ l1_w, unsigned short* __restrict__ l1_wT,
    const float* __restrict__ l2_w, unsigned short* __restrict__ l2_wT,
    const float* __restrict__ sc_w, unsigned short* __restrict__ sc_wT,
    const float* __restrict__ W3, const float* __restrict__ b3,
    float* __restrict__ st)
{
    __shared__ float tile[32][33];
    const int b = blockIdx.x;
    const int t = threadIdx.x;

    if (b < 8192) {
        int i = (b * 256 + t) * 4;
        float4 v = *(const float4*)(feats + i);
        ushort4 o;
        o.x = f2bf(v.x); o.y = f2bf(v.y); o.z = f2bf(v.z); o.w = f2bf(v.w);
        *(ushort4*)(featsb + i) = o;
    } else if (b < 8480) {
        int idx = b - 8192;
        transpose_body(l1_w, l1_wT, CMID, L1OUT, idx % 32, idx / 32, tile);
    } else if (b < 8992) {
        int idx = b - 8480;
        transpose_body(l2_w, l2_wT, L1OUT, COUTC, idx % 16, idx / 16, tile);
    } else if (b < 9120) {
        int idx = b - 8992;
        transpose_body(sc_w, sc_wT, CINC, COUTC, idx % 16, idx / 16, tile);
    } else {
        const int sb = b - 9120;
        const int lane = t & 63, wave = t >> 6;
        const int c0 = lane * 4;
        if (sb < 64) {
            int pair = sb * 4 + wave;
            int h = pair >> 4, hp = pair & 15;
            f32x4 a  = *(const f32x4*)(W3 + h * CINC + c0);
            f32x4 bb = *(const f32x4*)(W3 + hp * CINC + c0);
            float g = a[0] * bb[0] + a[1] * bb[1] + a[2] * bb[2] + a[3] * bb[3];
            #pragma unroll
            for (int off = 1; off < 64; off <<= 1) g += __shfl_xor(g, off);
            if (lane == 0) st[pair] = g * (1.f / CINC);
        } else if (sb == 64) {
            #pragma unroll
            for (int i = 0; i < 4; ++i) {
                int h = wave * 4 + i;
                f32x4 w  = *(const f32x4*)(W3 + h * CINC + c0);
                f32x4 bb = *(const f32x4*)(b3 + c0);
                float s  = w[0] + w[1] + w[2] + w[3];
                float sbv = w[0] * bb[0] + w[1] * bb[1] + w[2] * bb[2] + w[3] * bb[3];
                #pragma unroll
                for (int off = 1; off < 64; off <<= 1) { s += __shfl_xor(s, off); sbv += __shfl_xor(sbv, off); }
                if (lane == 0) { st[256 + h] = s * (1.f / CINC); st[272 + h] = sbv * (1.f / CINC); }
            }
        } else if (wave == 0) {
            f32x4 bb = *(const f32x4*)(b3 + c0);
            float s = bb[0] + bb[1] + bb[2] + bb[3];
            float q = bb[0] * bb[0] + bb[1] * bb[1] + bb[2] * bb[2] + bb[3] * bb[3];
            #pragma unroll
            for (int off = 1; off < 64; off <<= 1) { s += __shfl_xor(s, off); q += __shfl_xor(q, off); }
            if (lane == 0) { st[288] = s * (1.f / CINC); st[289] = q * (1.f / CINC); }
        }
    }
}

// ---------------------------------------------------------------------------
// Fused edge kernel, R11 (FROZEN — verified 155 us, VALUBusy 57%).
// ---------------------------------------------------------------------------
__global__ __launch_bounds__(256, 3) void edge_fused_kernel(
    const float* __restrict__ xyz, const unsigned short* __restrict__ featsb,
    const int* __restrict__ nei,
    const float* __restrict__ pe_w1, const float* __restrict__ pe_b1,
    const float* __restrict__ pe_g1, const float* __restrict__ pe_be1,
    const float* __restrict__ pe_w2, const float* __restrict__ pe_b2,
    const float* __restrict__ pe_g2, const float* __restrict__ pe_be2,
    const float* __restrict__ wn_w1, const float* __restrict__ wn_b1,
    const float* __restrict__ wn_g1, const float* __restrict__ wn_be1,
    const float* __restrict__ wn_w2, const float* __restrict__ wn_b2,
    const float* __restrict__ wn_g2, const float* __restrict__ wn_be2,
    const float* __restrict__ st,
    const float* __restrict__ wn_w3, const float* __restrict__ wn_b3,
    const float* __restrict__ wn_g3, const float* __restrict__ wn_be3,
    const float* __restrict__ nm_g, const float* __restrict__ nm_b,
    unsigned short* __restrict__ xln)
{
    __shared__ __align__(16) float W3s[16 * 256];             // 16 KB
    __shared__ __align__(16) float w2s[PBLK * W2LD];          // 17 KB [lp][hh*16+k]
    __shared__ __align__(16) float rms[PBLK * 16];
    __shared__ __align__(16) float mus[PBLK * 16];
    __shared__ float pes[PBLK * 32];

    const int t = threadIdx.x;

    // ---- async-stage wn_w3 into LDS; drained by the Phase-A/B barrier ----
    {
        const int lane = t & 63, wave = t >> 6;
        #pragma unroll
        for (int r = 0; r < 4; ++r) {
            int base = (wave * 4 + r) * 256;           // one 1KB row per iter
            gld_lds16f(wn_w3 + base + lane * 4, W3s + base);
        }
    }

    // ======================= Phase A: per-edge MLPs =======================
    {
        const int lp = t >> 4, kk = t & 15;
        const int m = blockIdx.x * PBLK + lp;
        const int n = nei[m * KNB + kk];
        const float lx = xyz[n * 3 + 0] - xyz[m * 3 + 0];
        const float ly = xyz[n * 3 + 1] - xyz[m * 3 + 1];
        const float lz = xyz[n * 3 + 2] - xyz[m * 3 + 2];

        // ---- WN layer 1 (scalar, small) -> pairs ----
        f32x2 w1p[8];
        float s = 0.f, q = 0.f;
        #pragma unroll
        for (int c4 = 0; c4 < 4; ++c4) {
            f32x4 wa = *(const f32x4*)&wn_w1[c4 * 4];
            f32x4 wb = *(const f32x4*)&wn_w1[16 + c4 * 4];
            f32x4 wc = *(const f32x4*)&wn_w1[32 + c4 * 4];
            f32x4 bb = *(const f32x4*)&wn_b1[c4 * 4];
            #pragma unroll
            for (int j = 0; j < 4; ++j) {
                float v = bb[j] + lx * wa[j] + ly * wb[j] + lz * wc[j];
                int c = c4 * 4 + j;
                w1p[c >> 1][c & 1] = v; s += v; q += v * v;
            }
        }
        float mu = s * (1.f / 16.f);
        float rstd = rsqrtf(q * (1.f / 16.f) - mu * mu + EPSLN);
        #pragma unroll
        for (int c4 = 0; c4 < 4; ++c4) {
            f32x4 g = *(const f32x4*)&wn_g1[c4 * 4];
            f32x4 be = *(const f32x4*)&wn_be1[c4 * 4];
            #pragma unroll
            for (int j = 0; j < 4; ++j) {
                int c = c4 * 4 + j;
                w1p[c >> 1][c & 1] = leaky((w1p[c >> 1][c & 1] - mu) * rstd * g[j] + be[j]);
            }
        }

        // ---- WN layer 2 (packed fma, weights via SGPR) ----
        f32x2 w2p[8];
        #pragma unroll
        for (int c4 = 0; c4 < 4; ++c4) {
            f32x4 bb = *(const f32x4*)&wn_b2[c4 * 4];
            w2p[c4 * 2] = lo2(bb); w2p[c4 * 2 + 1] = hi2(bb);
        }
        #pragma unroll 2
        for (int jp = 0; jp < 8; ++jp) {
            f32x2 hp = w1p[jp];
            #pragma unroll
            for (int c4 = 0; c4 < 4; ++c4) {
                f32x4 w = *(const f32x4*)&wn_w2[(2 * jp) * 16 + c4 * 4];
                pkfma_lo_s(w2p[c4 * 2], hp, lo2(w));
                pkfma_lo_s(w2p[c4 * 2 + 1], hp, hi2(w));
            }
            #pragma unroll
            for (int c4 = 0; c4 < 4; ++c4) {
                f32x4 w = *(const f32x4*)&wn_w2[(2 * jp + 1) * 16 + c4 * 4];
                pkfma_hi_s(w2p[c4 * 2], hp, lo2(w));
                pkfma_hi_s(w2p[c4 * 2 + 1], hp, hi2(w));
            }
        }
        s = 0.f; q = 0.f;
        #pragma unroll
        for (int i = 0; i < 8; ++i) {
            s += w2p[i][0] + w2p[i][1];
            q += w2p[i][0] * w2p[i][0] + w2p[i][1] * w2p[i][1];
        }
        mu = s * (1.f / 16.f);
        rstd = rsqrtf(q * (1.f / 16.f) - mu * mu + EPSLN);
        #pragma unroll
        for (int c4 = 0; c4 < 4; ++c4) {
            f32x4 g = *(const f32x4*)&wn_g2[c4 * 4];
            f32x4 be = *(const f32x4*)&wn_be2[c4 * 4];
            #pragma unroll
            for (int j = 0; j < 4; ++j) {
                int c = c4 * 4 + j;
                w2p[c >> 1][c & 1] = leaky((w2p[c >> 1][c & 1] - mu) * rstd * g[j] + be[j]);
            }
        }

        // ---- folded LN(256) stats (G matrix via SGPR operand) ----
        float mu3 = st[288];
        #pragma unroll
        for (int h4 = 0; h4 < 4; ++h4) {
            f32x4 wm = *(const f32x4*)&st[256 + h4 * 4];
            mu3 += wm[0] * w2p[h4 * 2][0] + wm[1] * w2p[h4 * 2][1]
                 + wm[2] * w2p[h4 * 2 + 1][0] + wm[3] * w2p[h4 * 2 + 1][1];
        }
        float esq = st[289];
        #pragma unroll 4
        for (int hh = 0; hh < 16; ++hh) {
            f32x2 acc2 = {0.f, 0.f};
            #pragma unroll
            for (int h4 = 0; h4 < 4; ++h4) {
                f32x4 g = *(const f32x4*)&st[hh * 16 + h4 * 4];
                pkfma_s0(acc2, lo2(g), w2p[h4 * 2]);
                pkfma_s0(acc2, hi2(g), w2p[h4 * 2 + 1]);
            }
            float acc = acc2[0] + acc2[1] + 2.f * st[272 + hh];
            esq += w2p[hh >> 1][hh & 1] * acc;
        }
        float r3 = rsqrtf(esq - mu3 * mu3 + EPSLN);

        #pragma unroll
        for (int hh = 0; hh < 16; ++hh)
            w2s[lp * W2LD + hh * 16 + kk] = w2p[hh >> 1][hh & 1];
        rms[lp * 16 + kk] = r3;
        mus[lp * 16 + kk] = mu3;

        // ---- PE layer 1 (scalar) -> pairs ----
        f32x2 h2[16];
        s = 0.f; q = 0.f;
        #pragma unroll
        for (int c4 = 0; c4 < 8; ++c4) {
            f32x4 wa = *(const f32x4*)&pe_w1[c4 * 4];
            f32x4 wb = *(const f32x4*)&pe_w1[32 + c4 * 4];
            f32x4 wc = *(const f32x4*)&pe_w1[64 + c4 * 4];
            f32x4 bb = *(const f32x4*)&pe_b1[c4 * 4];
            #pragma unroll
            for (int j = 0; j < 4; ++j) {
                float v = bb[j] + lx * wa[j] + ly * wb[j] + lz * wc[j];
                int c = c4 * 4 + j;
                h2[c >> 1][c & 1] = v; s += v; q += v * v;
            }
        }
        mu = s * (1.f / 32.f);
        rstd = rsqrtf(q * (1.f / 32.f) - mu * mu + EPSLN);
        #pragma unroll
        for (int c4 = 0; c4 < 8; ++c4) {
            f32x4 g = *(const f32x4*)&pe_g1[c4 * 4];
            f32x4 be = *(const f32x4*)&pe_be1[c4 * 4];
            #pragma unroll
            for (int j = 0; j < 4; ++j) {
                int c = c4 * 4 + j;
                h2[c >> 1][c & 1] = leaky((h2[c >> 1][c & 1] - mu) * rstd * g[j] + be[j]);
            }
        }

        // ---- PE layer 2 (packed fma, weights via SGPR) ----
        f32x2 f2[16];
        #pragma unroll
        for (int c4 = 0; c4 < 8; ++c4) {
            f32x4 bb = *(const f32x4*)&pe_b2[c4 * 4];
            f2[c4 * 2] = lo2(bb); f2[c4 * 2 + 1] = hi2(bb);
        }
        #pragma unroll 2
        for (int jp = 0; jp < 16; ++jp) {
            f32x2 hp = h2[jp];
            #pragma unroll
            for (int c4 = 0; c4 < 8; ++c4) {
                f32x4 w = *(const f32x4*)&pe_w2[(2 * jp) * 32 + c4 * 4];
                pkfma_lo_s(f2[c4 * 2], hp, lo2(w));
                pkfma_lo_s(f2[c4 * 2 + 1], hp, hi2(w));
            }
            #pragma unroll
            for (int c4 = 0; c4 < 8; ++c4) {
                f32x4 w = *(const f32x4*)&pe_w2[(2 * jp + 1) * 32 + c4 * 4];
                pkfma_hi_s(f2[c4 * 2], hp, lo2(w));
                pkfma_hi_s(f2[c4 * 2 + 1], hp, hi2(w));
            }
        }
        s = 0.f; q = 0.f;
        #pragma unroll
        for (int i = 0; i < 16; ++i) {
            s += f2[i][0] + f2[i][1];
            q += f2[i][0] * f2[i][0] + f2[i][1] * f2[i][1];
        }
        mu = s * (1.f / 32.f);
        rstd = rsqrtf(q * (1.f / 32.f) - mu * mu + EPSLN);
        #pragma unroll
        for (int c4 = 0; c4 < 8; ++c4) {
            f32x4 g = *(const f32x4*)&pe_g2[c4 * 4];
            f32x4 be = *(const f32x4*)&pe_be2[c4 * 4];
            #pragma unroll
            for (int j = 0; j < 4; ++j) {
                int c = c4 * 4 + j;
                float v = (f2[c >> 1][c & 1] - mu) * rstd * g[j] + be[j];
                v += __shfl_xor(v, 1);
                v += __shfl_xor(v, 2);
                v += __shfl_xor(v, 4);
                v += __shfl_xor(v, 8);
                if (kk == 0) pes[lp * 32 + c] = v;
            }
        }
    }
    __syncthreads();   // orders w2s/rms/mus/pes writes AND drains W3s async stage

    // ======================= Phase B: per-point aggregation ================
    const int lane = t & 63, wave = t >> 6;
    const int c0 = lane * 4;
    const f32x4 b3r  = *(const f32x4*)(wn_b3 + c0);
    const f32x4 g3r  = *(const f32x4*)(wn_g3 + c0);
    const f32x4 be3r = *(const f32x4*)(wn_be3 + c0);

    for (int pp = 0; pp < 4; ++pp) {
        const int lp = wave * 4 + pp;
        const int p  = blockIdx.x * PBLK + lp;
        const int* np = nei + p * KNB;

        // raw2[k][cp]: k = neighbor, cp = channel pair (c0+0/1, c0+2/3)
        f32x2 raw2[16][2];
        #pragma unroll
        for (int k = 0; k < 16; ++k) {
            raw2[k][0] = (f32x2){0.f, 0.f};
            raw2[k][1] = (f32x2){0.f, 0.f};
        }

        #pragma unroll 2
        for (int hh = 0; hh < 16; ++hh) {
            f32x4 w3r = *(const f32x4*)&W3s[hh * 256 + c0];
            f32x2 w01 = lo2(w3r), w23 = hi2(w3r);
            f32x4 u0 = *(const f32x4*)&w2s[lp * W2LD + hh * 16 + 0];
            f32x4 u1 = *(const f32x4*)&w2s[lp * W2LD + hh * 16 + 4];
            f32x4 u2 = *(const f32x4*)&w2s[lp * W2LD + hh * 16 + 8];
            f32x4 u3 = *(const f32x4*)&w2s[lp * W2LD + hh * 16 + 12];
            f32x2 p0 = lo2(u0), p1 = hi2(u0), p2 = lo2(u1), p3 = hi2(u1);
            f32x2 p4 = lo2(u2), p5 = hi2(u2), p6 = lo2(u3), p7 = hi2(u3);
            pkfma_lo(raw2[ 0][0], p0, w01); pkfma_lo(raw2[ 0][1], p0, w23);
            pkfma_hi(raw2[ 1][0], p0, w01); pkfma_hi(raw2[ 1][1], p0, w23);
            pkfma_lo(raw2[ 2][0], p1, w01); pkfma_lo(raw2[ 2][1], p1, w23);
            pkfma_hi(raw2[ 3][0], p1, w01); pkfma_hi(raw2[ 3][1], p1, w23);
            pkfma_lo(raw2[ 4][0], p2, w01); pkfma_lo(raw2[ 4][1], p2, w23);
            pkfma_hi(raw2[ 5][0], p2, w01); pkfma_hi(raw2[ 5][1], p2, w23);
            pkfma_lo(raw2[ 6][0], p3, w01); pkfma_lo(raw2[ 6][1], p3, w23);
            pkfma_hi(raw2[ 7][0], p3, w01); pkfma_hi(raw2[ 7][1], p3, w23);
            pkfma_lo(raw2[ 8][0], p4, w01); pkfma_lo(raw2[ 8][1], p4, w23);
            pkfma_hi(raw2[ 9][0], p4, w01); pkfma_hi(raw2[ 9][1], p4, w23);
            pkfma_lo(raw2[10][0], p5, w01); pkfma_lo(raw2[10][1], p5, w23);
            pkfma_hi(raw2[11][0], p5, w01); pkfma_hi(raw2[11][1], p5, w23);
            pkfma_lo(raw2[12][0], p6, w01); pkfma_lo(raw2[12][1], p6, w23);
            pkfma_hi(raw2[13][0], p6, w01); pkfma_hi(raw2[13][1], p6, w23);
            pkfma_lo(raw2[14][0], p7, w01); pkfma_lo(raw2[14][1], p7, w23);
            pkfma_hi(raw2[15][0], p7, w01); pkfma_hi(raw2[15][1], p7, w23);
        }

        float agg[4] = {0.f, 0.f, 0.f, 0.f};
        #pragma unroll
        for (int k4 = 0; k4 < 4; ++k4) {
            f32x4 rkv = *(const f32x4*)&rms[lp * 16 + k4 * 4];
            f32x4 muv = *(const f32x4*)&mus[lp * 16 + k4 * 4];
            #pragma unroll
            for (int r = 0; r < 4; ++r) {
                int k = k4 * 4 + r;
                int nk = np[k];
                float rk  = rkv[r];
                float muk = muv[r];
                ushort4 fu = *(const ushort4*)(featsb + (size_t)nk * CINC + c0);
                float w3x = (raw2[k][0][0] + b3r[0] - muk) * rk * g3r[0] + be3r[0];
                float w3y = (raw2[k][0][1] + b3r[1] - muk) * rk * g3r[1] + be3r[1];
                float w3z = (raw2[k][1][0] + b3r[2] - muk) * rk * g3r[2] + be3r[2];
                float w3w = (raw2[k][1][1] + b3r[3] - muk) * rk * g3r[3] + be3r[3];
                agg[0] += bf2f(fu.x) * w3x;
                agg[1] += bf2f(fu.y) * w3y;
                agg[2] += bf2f(fu.z) * w3z;
                agg[3] += bf2f(fu.w) * w3w;
            }
        }

        float pv = (lane < 32) ? pes[lp * 32 + lane] : 0.f;

        float s = agg[0] + agg[1] + agg[2] + agg[3];
        float q = agg[0] * agg[0] + agg[1] * agg[1] + agg[2] * agg[2] + agg[3] * agg[3];
        if (lane < 32) { s += pv; q += pv * pv; }
        #pragma unroll
        for (int off = 1; off < 64; off <<= 1) {
            s += __shfl_xor(s, off);
            q += __shfl_xor(q, off);
        }
        float mu = s * (1.f / 288.f);
        float rstd = rsqrtf(q * (1.f / 288.f) - mu * mu + EPSLN);

        f32x4 ngr = *(const f32x4*)(nm_g + c0);
        f32x4 nbr = *(const f32x4*)(nm_b + c0);
        unsigned short* xp = xln + (size_t)p * CMID;
        ushort4 o;
        o.x = f2bf((agg[0] - mu) * rstd * ngr[0] + nbr[0]);
        o.y = f2bf((agg[1] - mu) * rstd * ngr[1] + nbr[1]);
        o.z = f2bf((agg[2] - mu) * rstd * ngr[2] + nbr[2]);
        o.w = f2bf((agg[3] - mu) * rstd * ngr[3] + nbr[3]);
        *(ushort4*)(xp + c0) = o;
        if (lane < 32)
            xp[256 + lane] = f2bf((pv - mu) * rstd * nm_g[256 + lane] + nm_b[256 + lane]);
    }
}

// ---------------------------------------------------------------------------
// GEMM 1: h1 = leaky(xln @ l1_w + l1_b), bf16 MFMA, 128x128, BK=32
// + XCD swizzle (R13)
// ---------------------------------------------------------------------------
__global__ __launch_bounds__(256) void gemm1_mfma(
    const unsigned short* __restrict__ A,
    const unsigned short* __restrict__ BT,
    const float* __restrict__ bias,
    unsigned short* __restrict__ C)
{
    __shared__ unsigned short As[128 * 32];
    __shared__ unsigned short Bs[128 * 32];
    const int t = threadIdx.x;
    const int lane = t & 63, wave = t >> 6;
    const int wm = wave >> 1, wn = wave & 1;
    int bx, by;
    xcd_swz(L1OUT / 128, bx, by);
    const int m0 = by * 128, n0 = bx * 128;
    const int l15 = lane & 15, j0 = (lane >> 4) << 3;

    f32x4 zero = {0.f, 0.f, 0.f, 0.f};
    f32x4 acc[4][4];
    #pragma unroll
    for (int i = 0; i < 4; ++i)
        #pragma unroll
        for (int j = 0; j < 4; ++j) acc[i][j] = zero;

    for (int kt = 0; kt < CMID; kt += 32) {
        stage_tile(A,  CMID, m0, kt, As, wave, lane);
        stage_tile(BT, CMID, n0, kt, Bs, wave, lane);
        __syncthreads();
        short8 af[4], bf[4];
        #pragma unroll
        for (int i = 0; i < 4; ++i) {
            int ar = wm * 64 + i * 16 + l15;
            af[i] = *(const short8*)&As[ar * 32 + (j0 ^ ((ar & 3) << 3))];
            int br = wn * 64 + i * 16 + l15;
            bf[i] = *(const short8*)&Bs[br * 32 + (j0 ^ ((br & 3) << 3))];
        }
        #pragma unroll
        for (int i = 0; i < 4; ++i)
            #pragma unroll
            for (int j = 0; j < 4; ++j)
                acc[i][j] = __builtin_amdgcn_mfma_f32_16x16x32_bf16(af[i], bf[j], acc[i][j], 0, 0, 0);
        __syncthreads();
    }

    const int q = lane >> 4;
    #pragma unroll
    for (int j = 0; j < 4; ++j) {
        int ncol = n0 + wn * 64 + j * 16 + l15;
        float bv = bias[ncol];
        #pragma unroll
        for (int i = 0; i < 4; ++i) {
            int mbase = m0 + wm * 64 + i * 16 + q * 4;
            #pragma unroll
            for (int r = 0; r < 4; ++r)
                C[(size_t)(mbase + r) * L1OUT + ncol] = f2bf(leaky(acc[i][j][r] + bv));
        }
    }
}

// ---------------------------------------------------------------------------
// GEMM 2: out = leaky(h1 @ l2_w + feats @ sc_w + b2 + bsc), dual-K bf16 MFMA
// BK=32 (R12's BK=64 regressed — reverted) + XCD swizzle (R13)
// ---------------------------------------------------------------------------
__global__ __launch_bounds__(256) void gemm2_mfma(
    const unsigned short* __restrict__ H,
    const unsigned short* __restrict__ W2T,
    const unsigned short* __restrict__ F,
    const unsigned short* __restrict__ WscT,
    const float* __restrict__ b2, const float* __restrict__ bsc,
    float* __restrict__ Out)
{
    __shared__ unsigned short As[128 * 32];
    __shared__ unsigned short Bs[128 * 32];
    const int t = threadIdx.x;
    const int lane = t & 63, wave = t >> 6;
    const int wm = wave >> 1, wn = wave & 1;
    int bx, by;
    xcd_swz(COUTC / 128, bx, by);
    const int m0 = by * 128, n0 = bx * 128;
    const int l15 = lane & 15, j0 = (lane >> 4) << 3;

    f32x4 zero = {0.f, 0.f, 0.f, 0.f};
    f32x4 acc[4][4];
    #pragma unroll
    for (int i = 0; i < 4; ++i)
        #pragma unroll
        for (int j = 0; j < 4; ++j) acc[i][j] = zero;

    for (int kt = 0; kt < L1OUT; kt += 32) {
        stage_tile(H,   L1OUT, m0, kt, As, wave, lane);
        stage_tile(W2T, L1OUT, n0, kt, Bs, wave, lane);
        __syncthreads();
        short8 af[4], bf[4];
        #pragma unroll
        for (int i = 0; i < 4; ++i) {
            int ar = wm * 64 + i * 16 + l15;
            af[i] = *(const short8*)&As[ar * 32 + (j0 ^ ((ar & 3) << 3))];
            int br = wn * 64 + i * 16 + l15;
            bf[i] = *(const short8*)&Bs[br * 32 + (j0 ^ ((br & 3) << 3))];
        }
        #pragma unroll
        for (int i = 0; i < 4; ++i)
            #pragma unroll
            for (int j = 0; j < 4; ++j)
                acc[i][j] = __builtin_amdgcn_mfma_f32_16x16x32_bf16(af[i], bf[j], acc[i][j], 0, 0, 0);
        __syncthreads();
    }
    for (int kt = 0; kt < CINC; kt += 32) {
        stage_tile(F,    CINC, m0, kt, As, wave, lane);
        stage_tile(WscT, CINC, n0, kt, Bs, wave, lane);
        __syncthreads();
        short8 af[4], bf[4];
        #pragma unroll
        for (int i = 0; i < 4; ++i) {
            int ar = wm * 64 + i * 16 + l15;
            af[i] = *(const short8*)&As[ar * 32 + (j0 ^ ((ar & 3) << 3))];
            int br = wn * 64 + i * 16 + l15;
            bf[i] = *(const short8*)&Bs[br * 32 + (j0 ^ ((br & 3) << 3))];
        }
        #pragma unroll
        for (int i = 0; i < 4; ++i)
            #pragma unroll
            for (int j = 0; j < 4; ++j)
                acc[i][j] = __builtin_amdgcn_mfma_f32_16x16x32_bf16(af[i], bf[j], acc[i][j], 0, 0, 0);
        __syncthreads();
    }

    const int q = lane >> 4;
    #pragma unroll
    for (int j = 0; j < 4; ++j) {
        int ncol = n0 + wn * 64 + j * 16 + l15;
        float bv = b2[ncol] + bsc[ncol];
        #pragma unroll
        for (int i = 0; i < 4; ++i) {
            int mbase = m0 + wm * 64 + i * 16 + q * 4;
            #pragma unroll
            for (int r = 0; r < 4; ++r)
                Out[(size_t)(mbase + r) * COUTC + ncol] = leaky(acc[i][j][r] + bv);
        }
    }
}

extern "C" void kernel_launch(void* const* d_in, const int* in_sizes, int n_in,
                              void* d_out, int out_size, void* d_ws, size_t ws_size,
                              hipStream_t stream)
{
    const float* xyz    = (const float*)d_in[0];
    const float* feats  = (const float*)d_in[1];
    const int*   nei    = (const int*)d_in[2];
    const float* pe_w1  = (const float*)d_in[3];
    const float* pe_b1  = (const float*)d_in[4];
    const float* pe_g1  = (const float*)d_in[5];
    const float* pe_be1 = (const float*)d_in[6];
    const float* pe_w2  = (const float*)d_in[7];
    const float* pe_b2  = (const float*)d_in[8];
    const float* pe_g2  = (const float*)d_in[9];
    const float* pe_be2 = (const float*)d_in[10];
    const float* wn_w1  = (const float*)d_in[11];
    const float* wn_b1  = (const float*)d_in[12];
    const float* wn_g1  = (const float*)d_in[13];
    const float* wn_be1 = (const float*)d_in[14];
    const float* wn_w2  = (const float*)d_in[15];
    const float* wn_b2  = (const float*)d_in[16];
    const float* wn_g2  = (const float*)d_in[17];
    const float* wn_be2 = (const float*)d_in[18];
    const float* wn_w3  = (const float*)d_in[19];
    const float* wn_b3  = (const float*)d_in[20];
    const float* wn_g3  = (const float*)d_in[21];
    const float* wn_be3 = (const float*)d_in[22];
    const float* nm_g   = (const float*)d_in[23];
    const float* nm_b   = (const float*)d_in[24];
    const float* l1_w   = (const float*)d_in[25];
    const float* l1_b   = (const float*)d_in[26];
    const float* l2_w   = (const float*)d_in[27];
    const float* l2_b   = (const float*)d_in[28];
    const float* sc_w   = (const float*)d_in[29];
    const float* sc_b   = (const float*)d_in[30];

    char* ws = (char*)d_ws;
    unsigned short* xln    = (unsigned short*)(ws);               // 18,874,368
    unsigned short* featsb = (unsigned short*)(ws + 18874368);    // 16,777,216
    unsigned short* l1_wT  = (unsigned short*)(ws + 35651584);    //    589,824
    unsigned short* l2_wT  = (unsigned short*)(ws + 36241408);    //  1,048,576
    unsigned short* sc_wT  = (unsigned short*)(ws + 37289984);    //    262,144
    float*          st     = (float*)(ws + 37552128);             //      4,096
    unsigned short* h1     = (unsigned short*)(ws + 37556224);    // 67,108,864

    prep_kernel<<<9186, 256, 0, stream>>>(
        feats, featsb, l1_w, l1_wT, l2_w, l2_wT, sc_w, sc_wT, wn_w3, wn_b3, st);

    edge_fused_kernel<<<NPTS / PBLK, 256, 0, stream>>>(
        xyz, featsb, nei,
        pe_w1, pe_b1, pe_g1, pe_be1, pe_w2, pe_b2, pe_g2, pe_be2,
        wn_w1, wn_b1, wn_g1, wn_be1, wn_w2, wn_b2, wn_g2, wn_be2,
        st, wn_w3, wn_b3, wn_g3, wn_be3, nm_g, nm_b, xln);

    gemm1_mfma<<<dim3(L1OUT / 128, NPTS / 128), 256, 0, stream>>>(xln, l1_wT, l1_b, h1);

    gemm2_mfma<<<dim3(COUTC / 128, NPTS / 128), 256, 0, stream>>>(
        h1, l2_wT, featsb, sc_wT, l2_b, sc_b, (float*)d_out);
}

// Round 8
// 376.440 us; speedup vs baseline: 1.1044x; 1.0037x over previous
//
#include <hip/hip_runtime.h>

#define NPTS  32768
#define KNB   16
#define CINC  256
#define PEC   32
#define HWN   16
#define CMID  288
#define L1OUT 1024
#define COUTC 512
#define EPSLN 1e-5f
#define PBLK  16
#define W2LD  272   // w2s leading dim (mod 32 == 16 -> 2-way write conflict, free)

typedef __attribute__((ext_vector_type(8))) short short8;
typedef __attribute__((ext_vector_type(4))) float f32x4;
typedef __attribute__((ext_vector_type(2))) float f32x2;

__device__ __forceinline__ float leaky(float x) { return x > 0.f ? x : 0.1f * x; }

__device__ __forceinline__ float bf2f(unsigned short u) {
    union { unsigned int i; float f; } x; x.i = ((unsigned int)u) << 16; return x.f;
}
__device__ __forceinline__ unsigned short f2bf(float f) {
    unsigned int x = __float_as_uint(f);
    x = (x + 0x7fffu + ((x >> 16) & 1u)) >> 16;
    return (unsigned short)x;
}

__device__ __forceinline__ f32x2 lo2(f32x4 v) { return __builtin_shufflevector(v, v, 0, 1); }
__device__ __forceinline__ f32x2 hi2(f32x4 v) { return __builtin_shufflevector(v, v, 2, 3); }

// ---- packed fp32 FMA (VOP3P). Elementwise: d += a*b (all VGPR) ----
__device__ __forceinline__ void pkfma(f32x2& d, f32x2 a, f32x2 b) {
    asm("v_pk_fma_f32 %0, %1, %2, %0" : "+v"(d) : "v"(a), "v"(b));
}
__device__ __forceinline__ void pkfma_lo(f32x2& d, f32x2 a, f32x2 b) {
    asm("v_pk_fma_f32 %0, %1, %2, %0 op_sel:[0,0,0] op_sel_hi:[0,1,1]" : "+v"(d) : "v"(a), "v"(b));
}
__device__ __forceinline__ void pkfma_hi(f32x2& d, f32x2 a, f32x2 b) {
    asm("v_pk_fma_f32 %0, %1, %2, %0 op_sel:[1,0,0] op_sel_hi:[1,1,1]" : "+v"(d) : "v"(a), "v"(b));
}
// ---- scalar-operand variants: weight operand consumed from SGPR pair ----
__device__ __forceinline__ void pkfma_lo_s(f32x2& d, f32x2 a, f32x2 b) {
    asm("v_pk_fma_f32 %0, %1, %2, %0 op_sel:[0,0,0] op_sel_hi:[0,1,1]" : "+v"(d) : "v"(a), "s"(b));
}
__device__ __forceinline__ void pkfma_hi_s(f32x2& d, f32x2 a, f32x2 b) {
    asm("v_pk_fma_f32 %0, %1, %2, %0 op_sel:[1,0,0] op_sel_hi:[1,1,1]" : "+v"(d) : "v"(a), "s"(b));
}
__device__ __forceinline__ void pkfma_s0(f32x2& d, f32x2 a, f32x2 b) {
    asm("v_pk_fma_f32 %0, %1, %2, %0" : "+v"(d) : "s"(a), "v"(b));
}

// async global->LDS, 16B per lane, dest = wave-uniform base + lane*16
__device__ __forceinline__ void gld_lds16(const unsigned short* g, unsigned short* l) {
    __builtin_amdgcn_global_load_lds(
        (const __attribute__((address_space(1))) unsigned int*)g,
        (__attribute__((address_space(3))) unsigned int*)l,
        16, 0, 0);
}
__device__ __forceinline__ void gld_lds16f(const float* g, float* l) {
    __builtin_amdgcn_global_load_lds(
        (const __attribute__((address_space(1))) unsigned int*)g,
        (__attribute__((address_space(3))) unsigned int*)l,
        16, 0, 0);
}

// BK=32 staging (128x32 tile), XOR swz (row&3)<<3 matched by readers
__device__ __forceinline__ void stage_tile(const unsigned short* __restrict__ g,
                                           size_t ld, int row0, int k0,
                                           unsigned short* lds, int wave, int lane)
{
    #pragma unroll
    for (int r = 0; r < 2; ++r) {
        int e   = r * 2048 + wave * 512 + lane * 8;
        int row = e >> 5;
        int kp  = e & 31;
        int kl  = kp ^ ((row & 3) << 3);
        const unsigned short* src = g + (size_t)(row0 + row) * ld + (k0 + kl);
        gld_lds16(src, lds + r * 2048 + wave * 512);
    }
}

// XCD-aware bijective swizzle (T1; nwg % 8 == 0)
__device__ __forceinline__ void xcd_swz(int gx, int& bx, int& by) {
    int lin = blockIdx.y * gx + blockIdx.x;
    int n   = gx * gridDim.y;
    int s   = (lin & 7) * (n >> 3) + (lin >> 3);
    bx = s % gx;
    by = s / gx;
}

// ---------------------------------------------------------------------------
// Merged prep kernel (R13, verified): feats->bf16 cvt, 3 weight transposes,
// wn3 stats in ONE launch. Block ranges:
//   [0, 8192) feats cvt | [8192, 8480) l1_w T | [8480, 8992) l2_w T
//   [8992, 9120) sc_w T | [9120, 9186) wn3 stats
// ---------------------------------------------------------------------------
__device__ __forceinline__ void transpose_body(
    const float* __restrict__ src, unsigned short* __restrict__ dst,
    int K, int N, int bx, int by, float (*tile)[33])
{
    const int k0 = by * 32, n0 = bx * 32;
    const int tx = threadIdx.x & 31, ty = threadIdx.x >> 5;
    #pragma unroll
    for (int i = ty; i < 32; i += 8)
        tile[i][tx] = src[(size_t)(k0 + i) * N + n0 + tx];
    __syncthreads();
    #pragma unroll
    for (int i = ty; i < 32; i += 8)
        dst[(size_t)(n0 + i) * K + k0 + tx] = f2bf(tile[tx][i]);
}

__global__ __launch_bounds__(256) void prep_kernel(
    const float* __restrict__ feats, unsigned short* __restrict__ featsb,
    const float* __restrict__ l1_w, unsigned short* __restrict__ l1_wT,
    const float* __restrict__ l2_w, unsigned short* __restrict__ l2_wT,
    const float* __restrict__ sc_w, unsigned short* __restrict__ sc_wT,
    const float* __restrict__ W3, const float* __restrict__ b3,
    float* __restrict__ st)
{
    __shared__ float tile[32][33];
    const int b = blockIdx.x;
    const int t = threadIdx.x;

    if (b < 8192) {
        int i = (b * 256 + t) * 4;
        float4 v = *(const float4*)(feats + i);
        ushort4 o;
        o.x = f2bf(v.x); o.y = f2bf(v.y); o.z = f2bf(v.z); o.w = f2bf(v.w);
        *(ushort4*)(featsb + i) = o;
    } else if (b < 8480) {
        int idx = b - 8192;
        transpose_body(l1_w, l1_wT, CMID, L1OUT, idx % 32, idx / 32, tile);
    } else if (b < 8992) {
        int idx = b - 8480;
        transpose_body(l2_w, l2_wT, L1OUT, COUTC, idx % 16, idx / 16, tile);
    } else if (b < 9120) {
        int idx = b - 8992;
        transpose_body(sc_w, sc_wT, CINC, COUTC, idx % 16, idx / 16, tile);
    } else {
        const int sb = b - 9120;
        const int lane = t & 63, wave = t >> 6;
        const int c0 = lane * 4;
        if (sb < 64) {
            int pair = sb * 4 + wave;
            int h = pair >> 4, hp = pair & 15;
            f32x4 a  = *(const f32x4*)(W3 + h * CINC + c0);
            f32x4 bb = *(const f32x4*)(W3 + hp * CINC + c0);
            float g = a[0] * bb[0] + a[1] * bb[1] + a[2] * bb[2] + a[3] * bb[3];
            #pragma unroll
            for (int off = 1; off < 64; off <<= 1) g += __shfl_xor(g, off);
            if (lane == 0) st[pair] = g * (1.f / CINC);
        } else if (sb == 64) {
            #pragma unroll
            for (int i = 0; i < 4; ++i) {
                int h = wave * 4 + i;
                f32x4 w  = *(const f32x4*)(W3 + h * CINC + c0);
                f32x4 bb = *(const f32x4*)(b3 + c0);
                float s  = w[0] + w[1] + w[2] + w[3];
                float sbv = w[0] * bb[0] + w[1] * bb[1] + w[2] * bb[2] + w[3] * bb[3];
                #pragma unroll
                for (int off = 1; off < 64; off <<= 1) { s += __shfl_xor(s, off); sbv += __shfl_xor(sbv, off); }
                if (lane == 0) { st[256 + h] = s * (1.f / CINC); st[272 + h] = sbv * (1.f / CINC); }
            }
        } else if (wave == 0) {
            f32x4 bb = *(const f32x4*)(b3 + c0);
            float s = bb[0] + bb[1] + bb[2] + bb[3];
            float q = bb[0] * bb[0] + bb[1] * bb[1] + bb[2] * bb[2] + bb[3] * bb[3];
            #pragma unroll
            for (int off = 1; off < 64; off <<= 1) { s += __shfl_xor(s, off); q += __shfl_xor(q, off); }
            if (lane == 0) { st[288] = s * (1.f / CINC); st[289] = q * (1.f / CINC); }
        }
    }
}

// ---------------------------------------------------------------------------
// Fused edge kernel, R11 (VERIFIED 151 us, VALUBusy 57% — R14 MFMA variant
// failed correctness and is retired; this is the counter-stable version).
// ---------------------------------------------------------------------------
__global__ __launch_bounds__(256, 3) void edge_fused_kernel(
    const float* __restrict__ xyz, const unsigned short* __restrict__ featsb,
    const int* __restrict__ nei,
    const float* __restrict__ pe_w1, const float* __restrict__ pe_b1,
    const float* __restrict__ pe_g1, const float* __restrict__ pe_be1,
    const float* __restrict__ pe_w2, const float* __restrict__ pe_b2,
    const float* __restrict__ pe_g2, const float* __restrict__ pe_be2,
    const float* __restrict__ wn_w1, const float* __restrict__ wn_b1,
    const float* __restrict__ wn_g1, const float* __restrict__ wn_be1,
    const float* __restrict__ wn_w2, const float* __restrict__ wn_b2,
    const float* __restrict__ wn_g2, const float* __restrict__ wn_be2,
    const float* __restrict__ st,
    const float* __restrict__ wn_w3, const float* __restrict__ wn_b3,
    const float* __restrict__ wn_g3, const float* __restrict__ wn_be3,
    const float* __restrict__ nm_g, const float* __restrict__ nm_b,
    unsigned short* __restrict__ xln)
{
    __shared__ __align__(16) float W3s[16 * 256];             // 16 KB
    __shared__ __align__(16) float w2s[PBLK * W2LD];          // 17 KB [lp][hh*16+k]
    __shared__ __align__(16) float rms[PBLK * 16];
    __shared__ __align__(16) float mus[PBLK * 16];
    __shared__ float pes[PBLK * 32];

    const int t = threadIdx.x;

    // ---- async-stage wn_w3 into LDS; drained by the Phase-A/B barrier ----
    {
        const int lane = t & 63, wave = t >> 6;
        #pragma unroll
        for (int r = 0; r < 4; ++r) {
            int base = (wave * 4 + r) * 256;           // one 1KB row per iter
            gld_lds16f(wn_w3 + base + lane * 4, W3s + base);
        }
    }

    // ======================= Phase A: per-edge MLPs =======================
    {
        const int lp = t >> 4, kk = t & 15;
        const int m = blockIdx.x * PBLK + lp;
        const int n = nei[m * KNB + kk];
        const float lx = xyz[n * 3 + 0] - xyz[m * 3 + 0];
        const float ly = xyz[n * 3 + 1] - xyz[m * 3 + 1];
        const float lz = xyz[n * 3 + 2] - xyz[m * 3 + 2];

        // ---- WN layer 1 (scalar, small) -> pairs ----
        f32x2 w1p[8];
        float s = 0.f, q = 0.f;
        #pragma unroll
        for (int c4 = 0; c4 < 4; ++c4) {
            f32x4 wa = *(const f32x4*)&wn_w1[c4 * 4];
            f32x4 wb = *(const f32x4*)&wn_w1[16 + c4 * 4];
            f32x4 wc = *(const f32x4*)&wn_w1[32 + c4 * 4];
            f32x4 bb = *(const f32x4*)&wn_b1[c4 * 4];
            #pragma unroll
            for (int j = 0; j < 4; ++j) {
                float v = bb[j] + lx * wa[j] + ly * wb[j] + lz * wc[j];
                int c = c4 * 4 + j;
                w1p[c >> 1][c & 1] = v; s += v; q += v * v;
            }
        }
        float mu = s * (1.f / 16.f);
        float rstd = rsqrtf(q * (1.f / 16.f) - mu * mu + EPSLN);
        #pragma unroll
        for (int c4 = 0; c4 < 4; ++c4) {
            f32x4 g = *(const f32x4*)&wn_g1[c4 * 4];
            f32x4 be = *(const f32x4*)&wn_be1[c4 * 4];
            #pragma unroll
            for (int j = 0; j < 4; ++j) {
                int c = c4 * 4 + j;
                w1p[c >> 1][c & 1] = leaky((w1p[c >> 1][c & 1] - mu) * rstd * g[j] + be[j]);
            }
        }

        // ---- WN layer 2 (packed fma, weights via SGPR) ----
        f32x2 w2p[8];
        #pragma unroll
        for (int c4 = 0; c4 < 4; ++c4) {
            f32x4 bb = *(const f32x4*)&wn_b2[c4 * 4];
            w2p[c4 * 2] = lo2(bb); w2p[c4 * 2 + 1] = hi2(bb);
        }
        #pragma unroll 2
        for (int jp = 0; jp < 8; ++jp) {
            f32x2 hp = w1p[jp];
            #pragma unroll
            for (int c4 = 0; c4 < 4; ++c4) {
                f32x4 w = *(const f32x4*)&wn_w2[(2 * jp) * 16 + c4 * 4];
                pkfma_lo_s(w2p[c4 * 2], hp, lo2(w));
                pkfma_lo_s(w2p[c4 * 2 + 1], hp, hi2(w));
            }
            #pragma unroll
            for (int c4 = 0; c4 < 4; ++c4) {
                f32x4 w = *(const f32x4*)&wn_w2[(2 * jp + 1) * 16 + c4 * 4];
                pkfma_hi_s(w2p[c4 * 2], hp, lo2(w));
                pkfma_hi_s(w2p[c4 * 2 + 1], hp, hi2(w));
            }
        }
        s = 0.f; q = 0.f;
        #pragma unroll
        for (int i = 0; i < 8; ++i) {
            s += w2p[i][0] + w2p[i][1];
            q += w2p[i][0] * w2p[i][0] + w2p[i][1] * w2p[i][1];
        }
        mu = s * (1.f / 16.f);
        rstd = rsqrtf(q * (1.f / 16.f) - mu * mu + EPSLN);
        #pragma unroll
        for (int c4 = 0; c4 < 4; ++c4) {
            f32x4 g = *(const f32x4*)&wn_g2[c4 * 4];
            f32x4 be = *(const f32x4*)&wn_be2[c4 * 4];
            #pragma unroll
            for (int j = 0; j < 4; ++j) {
                int c = c4 * 4 + j;
                w2p[c >> 1][c & 1] = leaky((w2p[c >> 1][c & 1] - mu) * rstd * g[j] + be[j]);
            }
        }

        // ---- folded LN(256) stats (G matrix via SGPR operand) ----
        float mu3 = st[288];
        #pragma unroll
        for (int h4 = 0; h4 < 4; ++h4) {
            f32x4 wm = *(const f32x4*)&st[256 + h4 * 4];
            mu3 += wm[0] * w2p[h4 * 2][0] + wm[1] * w2p[h4 * 2][1]
                 + wm[2] * w2p[h4 * 2 + 1][0] + wm[3] * w2p[h4 * 2 + 1][1];
        }
        float esq = st[289];
        #pragma unroll 4
        for (int hh = 0; hh < 16; ++hh) {
            f32x2 acc2 = {0.f, 0.f};
            #pragma unroll
            for (int h4 = 0; h4 < 4; ++h4) {
                f32x4 g = *(const f32x4*)&st[hh * 16 + h4 * 4];
                pkfma_s0(acc2, lo2(g), w2p[h4 * 2]);
                pkfma_s0(acc2, hi2(g), w2p[h4 * 2 + 1]);
            }
            float acc = acc2[0] + acc2[1] + 2.f * st[272 + hh];
            esq += w2p[hh >> 1][hh & 1] * acc;
        }
        float r3 = rsqrtf(esq - mu3 * mu3 + EPSLN);

        #pragma unroll
        for (int hh = 0; hh < 16; ++hh)
            w2s[lp * W2LD + hh * 16 + kk] = w2p[hh >> 1][hh & 1];
        rms[lp * 16 + kk] = r3;
        mus[lp * 16 + kk] = mu3;

        // ---- PE layer 1 (scalar) -> pairs ----
        f32x2 h2[16];
        s = 0.f; q = 0.f;
        #pragma unroll
        for (int c4 = 0; c4 < 8; ++c4) {
            f32x4 wa = *(const f32x4*)&pe_w1[c4 * 4];
            f32x4 wb = *(const f32x4*)&pe_w1[32 + c4 * 4];
            f32x4 wc = *(const f32x4*)&pe_w1[64 + c4 * 4];
            f32x4 bb = *(const f32x4*)&pe_b1[c4 * 4];
            #pragma unroll
            for (int j = 0; j < 4; ++j) {
                float v = bb[j] + lx * wa[j] + ly * wb[j] + lz * wc[j];
                int c = c4 * 4 + j;
                h2[c >> 1][c & 1] = v; s += v; q += v * v;
            }
        }
        mu = s * (1.f / 32.f);
        rstd = rsqrtf(q * (1.f / 32.f) - mu * mu + EPSLN);
        #pragma unroll
        for (int c4 = 0; c4 < 8; ++c4) {
            f32x4 g = *(const f32x4*)&pe_g1[c4 * 4];
            f32x4 be = *(const f32x4*)&pe_be1[c4 * 4];
            #pragma unroll
            for (int j = 0; j < 4; ++j) {
                int c = c4 * 4 + j;
                h2[c >> 1][c & 1] = leaky((h2[c >> 1][c & 1] - mu) * rstd * g[j] + be[j]);
            }
        }

        // ---- PE layer 2 (packed fma, weights via SGPR) ----
        f32x2 f2[16];
        #pragma unroll
        for (int c4 = 0; c4 < 8; ++c4) {
            f32x4 bb = *(const f32x4*)&pe_b2[c4 * 4];
            f2[c4 * 2] = lo2(bb); f2[c4 * 2 + 1] = hi2(bb);
        }
        #pragma unroll 2
        for (int jp = 0; jp < 16; ++jp) {
            f32x2 hp = h2[jp];
            #pragma unroll
            for (int c4 = 0; c4 < 8; ++c4) {
                f32x4 w = *(const f32x4*)&pe_w2[(2 * jp) * 32 + c4 * 4];
                pkfma_lo_s(f2[c4 * 2], hp, lo2(w));
                pkfma_lo_s(f2[c4 * 2 + 1], hp, hi2(w));
            }
            #pragma unroll
            for (int c4 = 0; c4 < 8; ++c4) {
                f32x4 w = *(const f32x4*)&pe_w2[(2 * jp + 1) * 32 + c4 * 4];
                pkfma_hi_s(f2[c4 * 2], hp, lo2(w));
                pkfma_hi_s(f2[c4 * 2 + 1], hp, hi2(w));
            }
        }
        s = 0.f; q = 0.f;
        #pragma unroll
        for (int i = 0; i < 16; ++i) {
            s += f2[i][0] + f2[i][1];
            q += f2[i][0] * f2[i][0] + f2[i][1] * f2[i][1];
        }
        mu = s * (1.f / 32.f);
        rstd = rsqrtf(q * (1.f / 32.f) - mu * mu + EPSLN);
        #pragma unroll
        for (int c4 = 0; c4 < 8; ++c4) {
            f32x4 g = *(const f32x4*)&pe_g2[c4 * 4];
            f32x4 be = *(const f32x4*)&pe_be2[c4 * 4];
            #pragma unroll
            for (int j = 0; j < 4; ++j) {
                int c = c4 * 4 + j;
                float v = (f2[c >> 1][c & 1] - mu) * rstd * g[j] + be[j];
                v += __shfl_xor(v, 1);
                v += __shfl_xor(v, 2);
                v += __shfl_xor(v, 4);
                v += __shfl_xor(v, 8);
                if (kk == 0) pes[lp * 32 + c] = v;
            }
        }
    }
    __syncthreads();   // orders w2s/rms/mus/pes writes AND drains W3s async stage

    // ======================= Phase B: per-point aggregation ================
    const int lane = t & 63, wave = t >> 6;
    const int c0 = lane * 4;
    const f32x4 b3r  = *(const f32x4*)(wn_b3 + c0);
    const f32x4 g3r  = *(const f32x4*)(wn_g3 + c0);
    const f32x4 be3r = *(const f32x4*)(wn_be3 + c0);

    for (int pp = 0; pp < 4; ++pp) {
        const int lp = wave * 4 + pp;
        const int p  = blockIdx.x * PBLK + lp;
        const int* np = nei + p * KNB;

        // raw2[k][cp]: k = neighbor, cp = channel pair (c0+0/1, c0+2/3)
        f32x2 raw2[16][2];
        #pragma unroll
        for (int k = 0; k < 16; ++k) {
            raw2[k][0] = (f32x2){0.f, 0.f};
            raw2[k][1] = (f32x2){0.f, 0.f};
        }

        #pragma unroll 2
        for (int hh = 0; hh < 16; ++hh) {
            f32x4 w3r = *(const f32x4*)&W3s[hh * 256 + c0];
            f32x2 w01 = lo2(w3r), w23 = hi2(w3r);
            f32x4 u0 = *(const f32x4*)&w2s[lp * W2LD + hh * 16 + 0];
            f32x4 u1 = *(const f32x4*)&w2s[lp * W2LD + hh * 16 + 4];
            f32x4 u2 = *(const f32x4*)&w2s[lp * W2LD + hh * 16 + 8];
            f32x4 u3 = *(const f32x4*)&w2s[lp * W2LD + hh * 16 + 12];
            f32x2 p0 = lo2(u0), p1 = hi2(u0), p2 = lo2(u1), p3 = hi2(u1);
            f32x2 p4 = lo2(u2), p5 = hi2(u2), p6 = lo2(u3), p7 = hi2(u3);
            pkfma_lo(raw2[ 0][0], p0, w01); pkfma_lo(raw2[ 0][1], p0, w23);
            pkfma_hi(raw2[ 1][0], p0, w01); pkfma_hi(raw2[ 1][1], p0, w23);
            pkfma_lo(raw2[ 2][0], p1, w01); pkfma_lo(raw2[ 2][1], p1, w23);
            pkfma_hi(raw2[ 3][0], p1, w01); pkfma_hi(raw2[ 3][1], p1, w23);
            pkfma_lo(raw2[ 4][0], p2, w01); pkfma_lo(raw2[ 4][1], p2, w23);
            pkfma_hi(raw2[ 5][0], p2, w01); pkfma_hi(raw2[ 5][1], p2, w23);
            pkfma_lo(raw2[ 6][0], p3, w01); pkfma_lo(raw2[ 6][1], p3, w23);
            pkfma_hi(raw2[ 7][0], p3, w01); pkfma_hi(raw2[ 7][1], p3, w23);
            pkfma_lo(raw2[ 8][0], p4, w01); pkfma_lo(raw2[ 8][1], p4, w23);
            pkfma_hi(raw2[ 9][0], p4, w01); pkfma_hi(raw2[ 9][1], p4, w23);
            pkfma_lo(raw2[10][0], p5, w01); pkfma_lo(raw2[10][1], p5, w23);
            pkfma_hi(raw2[11][0], p5, w01); pkfma_hi(raw2[11][1], p5, w23);
            pkfma_lo(raw2[12][0], p6, w01); pkfma_lo(raw2[12][1], p6, w23);
            pkfma_hi(raw2[13][0], p6, w01); pkfma_hi(raw2[13][1], p6, w23);
            pkfma_lo(raw2[14][0], p7, w01); pkfma_lo(raw2[14][1], p7, w23);
            pkfma_hi(raw2[15][0], p7, w01); pkfma_hi(raw2[15][1], p7, w23);
        }

        float agg[4] = {0.f, 0.f, 0.f, 0.f};
        #pragma unroll
        for (int k4 = 0; k4 < 4; ++k4) {
            f32x4 rkv = *(const f32x4*)&rms[lp * 16 + k4 * 4];
            f32x4 muv = *(const f32x4*)&mus[lp * 16 + k4 * 4];
            #pragma unroll
            for (int r = 0; r < 4; ++r) {
                int k = k4 * 4 + r;
                int nk = np[k];
                float rk  = rkv[r];
                float muk = muv[r];
                ushort4 fu = *(const ushort4*)(featsb + (size_t)nk * CINC + c0);
                float w3x = (raw2[k][0][0] + b3r[0] - muk) * rk * g3r[0] + be3r[0];
                float w3y = (raw2[k][0][1] + b3r[1] - muk) * rk * g3r[1] + be3r[1];
                float w3z = (raw2[k][1][0] + b3r[2] - muk) * rk * g3r[2] + be3r[2];
                float w3w = (raw2[k][1][1] + b3r[3] - muk) * rk * g3r[3] + be3r[3];
                agg[0] += bf2f(fu.x) * w3x;
                agg[1] += bf2f(fu.y) * w3y;
                agg[2] += bf2f(fu.z) * w3z;
                agg[3] += bf2f(fu.w) * w3w;
            }
        }

        float pv = (lane < 32) ? pes[lp * 32 + lane] : 0.f;

        float s = agg[0] + agg[1] + agg[2] + agg[3];
        float q = agg[0] * agg[0] + agg[1] * agg[1] + agg[2] * agg[2] + agg[3] * agg[3];
        if (lane < 32) { s += pv; q += pv * pv; }
        #pragma unroll
        for (int off = 1; off < 64; off <<= 1) {
            s += __shfl_xor(s, off);
            q += __shfl_xor(q, off);
        }
        float mu = s * (1.f / 288.f);
        float rstd = rsqrtf(q * (1.f / 288.f) - mu * mu + EPSLN);

        f32x4 ngr = *(const f32x4*)(nm_g + c0);
        f32x4 nbr = *(const f32x4*)(nm_b + c0);
        unsigned short* xp = xln + (size_t)p * CMID;
        ushort4 o;
        o.x = f2bf((agg[0] - mu) * rstd * ngr[0] + nbr[0]);
        o.y = f2bf((agg[1] - mu) * rstd * ngr[1] + nbr[1]);
        o.z = f2bf((agg[2] - mu) * rstd * ngr[2] + nbr[2]);
        o.w = f2bf((agg[3] - mu) * rstd * ngr[3] + nbr[3]);
        *(ushort4*)(xp + c0) = o;
        if (lane < 32)
            xp[256 + lane] = f2bf((pv - mu) * rstd * nm_g[256 + lane] + nm_b[256 + lane]);
    }
}

// ---------------------------------------------------------------------------
// GEMM 1: h1 = leaky(xln @ l1_w + l1_b), bf16 MFMA, 128x128, BK=32
// + XCD swizzle (R13, verified)
// ---------------------------------------------------------------------------
__global__ __launch_bounds__(256) void gemm1_mfma(
    const unsigned short* __restrict__ A,
    const unsigned short* __restrict__ BT,
    const float* __restrict__ bias,
    unsigned short* __restrict__ C)
{
    __shared__ unsigned short As[128 * 32];
    __shared__ unsigned short Bs[128 * 32];
    const int t = threadIdx.x;
    const int lane = t & 63, wave = t >> 6;
    const int wm = wave >> 1, wn = wave & 1;
    int bx, by;
    xcd_swz(L1OUT / 128, bx, by);
    const int m0 = by * 128, n0 = bx * 128;
    const int l15 = lane & 15, j0 = (lane >> 4) << 3;

    f32x4 zero = {0.f, 0.f, 0.f, 0.f};
    f32x4 acc[4][4];
    #pragma unroll
    for (int i = 0; i < 4; ++i)
        #pragma unroll
        for (int j = 0; j < 4; ++j) acc[i][j] = zero;

    for (int kt = 0; kt < CMID; kt += 32) {
        stage_tile(A,  CMID, m0, kt, As, wave, lane);
        stage_tile(BT, CMID, n0, kt, Bs, wave, lane);
        __syncthreads();
        short8 af[4], bf[4];
        #pragma unroll
        for (int i = 0; i < 4; ++i) {
            int ar = wm * 64 + i * 16 + l15;
            af[i] = *(const short8*)&As[ar * 32 + (j0 ^ ((ar & 3) << 3))];
            int br = wn * 64 + i * 16 + l15;
            bf[i] = *(const short8*)&Bs[br * 32 + (j0 ^ ((br & 3) << 3))];
        }
        #pragma unroll
        for (int i = 0; i < 4; ++i)
            #pragma unroll
            for (int j = 0; j < 4; ++j)
                acc[i][j] = __builtin_amdgcn_mfma_f32_16x16x32_bf16(af[i], bf[j], acc[i][j], 0, 0, 0);
        __syncthreads();
    }

    const int q = lane >> 4;
    #pragma unroll
    for (int j = 0; j < 4; ++j) {
        int ncol = n0 + wn * 64 + j * 16 + l15;
        float bv = bias[ncol];
        #pragma unroll
        for (int i = 0; i < 4; ++i) {
            int mbase = m0 + wm * 64 + i * 16 + q * 4;
            #pragma unroll
            for (int r = 0; r < 4; ++r)
                C[(size_t)(mbase + r) * L1OUT + ncol] = f2bf(leaky(acc[i][j][r] + bv));
        }
    }
}

// ---------------------------------------------------------------------------
// GEMM 2: dual-K bf16 MFMA, 128x128, BK=32 + XCD swizzle (R13, verified)
// ---------------------------------------------------------------------------
__global__ __launch_bounds__(256) void gemm2_mfma(
    const unsigned short* __restrict__ H,
    const unsigned short* __restrict__ W2T,
    const unsigned short* __restrict__ F,
    const unsigned short* __restrict__ WscT,
    const float* __restrict__ b2, const float* __restrict__ bsc,
    float* __restrict__ Out)
{
    __shared__ unsigned short As[128 * 32];
    __shared__ unsigned short Bs[128 * 32];
    const int t = threadIdx.x;
    const int lane = t & 63, wave = t >> 6;
    const int wm = wave >> 1, wn = wave & 1;
    int bx, by;
    xcd_swz(COUTC / 128, bx, by);
    const int m0 = by * 128, n0 = bx * 128;
    const int l15 = lane & 15, j0 = (lane >> 4) << 3;

    f32x4 zero = {0.f, 0.f, 0.f, 0.f};
    f32x4 acc[4][4];
    #pragma unroll
    for (int i = 0; i < 4; ++i)
        #pragma unroll
        for (int j = 0; j < 4; ++j) acc[i][j] = zero;

    for (int kt = 0; kt < L1OUT; kt += 32) {
        stage_tile(H,   L1OUT, m0, kt, As, wave, lane);
        stage_tile(W2T, L1OUT, n0, kt, Bs, wave, lane);
        __syncthreads();
        short8 af[4], bf[4];
        #pragma unroll
        for (int i = 0; i < 4; ++i) {
            int ar = wm * 64 + i * 16 + l15;
            af[i] = *(const short8*)&As[ar * 32 + (j0 ^ ((ar & 3) << 3))];
            int br = wn * 64 + i * 16 + l15;
            bf[i] = *(const short8*)&Bs[br * 32 + (j0 ^ ((br & 3) << 3))];
        }
        #pragma unroll
        for (int i = 0; i < 4; ++i)
            #pragma unroll
            for (int j = 0; j < 4; ++j)
                acc[i][j] = __builtin_amdgcn_mfma_f32_16x16x32_bf16(af[i], bf[j], acc[i][j], 0, 0, 0);
        __syncthreads();
    }
    for (int kt = 0; kt < CINC; kt += 32) {
        stage_tile(F,    CINC, m0, kt, As, wave, lane);
        stage_tile(WscT, CINC, n0, kt, Bs, wave, lane);
        __syncthreads();
        short8 af[4], bf[4];
        #pragma unroll
        for (int i = 0; i < 4; ++i) {
            int ar = wm * 64 + i * 16 + l15;
            af[i] = *(const short8*)&As[ar * 32 + (j0 ^ ((ar & 3) << 3))];
            int br = wn * 64 + i * 16 + l15;
            bf[i] = *(const short8*)&Bs[br * 32 + (j0 ^ ((br & 3) << 3))];
        }
        #pragma unroll
        for (int i = 0; i < 4; ++i)
            #pragma unroll
            for (int j = 0; j < 4; ++j)
                acc[i][j] = __builtin_amdgcn_mfma_f32_16x16x32_bf16(af[i], bf[j], acc[i][j], 0, 0, 0);
        __syncthreads();
    }

    const int q = lane >> 4;
    #pragma unroll
    for (int j = 0; j < 4; ++j) {
        int ncol = n0 + wn * 64 + j * 16 + l15;
        float bv = b2[ncol] + bsc[ncol];
        #pragma unroll
        for (int i = 0; i < 4; ++i) {
            int mbase = m0 + wm * 64 + i * 16 + q * 4;
            #pragma unroll
            for (int r = 0; r < 4; ++r)
                Out[(size_t)(mbase + r) * COUTC + ncol] = leaky(acc[i][j][r] + bv);
        }
    }
}

extern "C" void kernel_launch(void* const* d_in, const int* in_sizes, int n_in,
                              void* d_out, int out_size, void* d_ws, size_t ws_size,
                              hipStream_t stream)
{
    const float* xyz    = (const float*)d_in[0];
    const float* feats  = (const float*)d_in[1];
    const int*   nei    = (const int*)d_in[2];
    const float* pe_w1  = (const float*)d_in[3];
    const float* pe_b1  = (const float*)d_in[4];
    const float* pe_g1  = (const float*)d_in[5];
    const float* pe_be1 = (const float*)d_in[6];
    const float* pe_w2  = (const float*)d_in[7];
    const float* pe_b2  = (const float*)d_in[8];
    const float* pe_g2  = (const float*)d_in[9];
    const float* pe_be2 = (const float*)d_in[10];
    const float* wn_w1  = (const float*)d_in[11];
    const float* wn_b1  = (const float*)d_in[12];
    const float* wn_g1  = (const float*)d_in[13];
    const float* wn_be1 = (const float*)d_in[14];
    const float* wn_w2  = (const float*)d_in[15];
    const float* wn_b2  = (const float*)d_in[16];
    const float* wn_g2  = (const float*)d_in[17];
    const float* wn_be2 = (const float*)d_in[18];
    const float* wn_w3  = (const float*)d_in[19];
    const float* wn_b3  = (const float*)d_in[20];
    const float* wn_g3  = (const float*)d_in[21];
    const float* wn_be3 = (const float*)d_in[22];
    const float* nm_g   = (const float*)d_in[23];
    const float* nm_b   = (const float*)d_in[24];
    const float* l1_w   = (const float*)d_in[25];
    const float* l1_b   = (const float*)d_in[26];
    const float* l2_w   = (const float*)d_in[27];
    const float* l2_b   = (const float*)d_in[28];
    const float* sc_w   = (const float*)d_in[29];
    const float* sc_b   = (const float*)d_in[30];

    char* ws = (char*)d_ws;
    unsigned short* xln    = (unsigned short*)(ws);               // 18,874,368
    unsigned short* featsb = (unsigned short*)(ws + 18874368);    // 16,777,216
    unsigned short* l1_wT  = (unsigned short*)(ws + 35651584);    //    589,824
    unsigned short* l2_wT  = (unsigned short*)(ws + 36241408);    //  1,048,576
    unsigned short* sc_wT  = (unsigned short*)(ws + 37289984);    //    262,144
    float*          st     = (float*)(ws + 37552128);             //      4,096
    unsigned short* h1     = (unsigned short*)(ws + 37556224);    // 67,108,864

    prep_kernel<<<9186, 256, 0, stream>>>(
        feats, featsb, l1_w, l1_wT, l2_w, l2_wT, sc_w, sc_wT, wn_w3, wn_b3, st);

    edge_fused_kernel<<<NPTS / PBLK, 256, 0, stream>>>(
        xyz, featsb, nei,
        pe_w1, pe_b1, pe_g1, pe_be1, pe_w2, pe_b2, pe_g2, pe_be2,
        wn_w1, wn_b1, wn_g1, wn_be1, wn_w2, wn_b2, wn_g2, wn_be2,
        st, wn_w3, wn_b3, wn_g3, wn_be3, nm_g, nm_b, xln);

    gemm1_mfma<<<dim3(L1OUT / 128, NPTS / 128), 256, 0, stream>>>(xln, l1_wT, l1_b, h1);

    gemm2_mfma<<<dim3(COUTC / 128, NPTS / 128), 256, 0, stream>>>(
        h1, l2_wT, featsb, sc_wT, l2_b, sc_b, (float*)d_out);
}